// Round 2
// baseline (257.012 us; speedup 1.0000x reference)
//
#include <hip/hip_runtime.h>
#include <math.h>

#define B_DIM 4
#define L_DIM 8192
#define H_DIM 256
#define P_DIM 256
#define M_DIM (B_DIM * L_DIM)   // 32768 rows (b,l) flattened
#define NC 64                   // scan chunks per chain
#define LC 128                  // chunk length (NC*LC = L)

typedef __attribute__((ext_vector_type(8))) short bf16x8;
typedef __attribute__((ext_vector_type(4))) float f32x4;
typedef __attribute__((ext_vector_type(8))) unsigned short u16x8;

static __device__ __forceinline__ float bf2f(unsigned int u) {
    union { unsigned int i; float f; } v; v.i = u << 16; return v.f;
}
static __device__ __forceinline__ unsigned short f2bf(float f) {
    union { float f; unsigned int i; } v; v.f = f;
    unsigned int r = v.i + 0x7FFFu + ((v.i >> 16) & 1u);
    return (unsigned short)(r >> 16);
}
// tanh-form GELU; |gelu_tanh - gelu_erf| <= ~0.003 absolute, far under threshold
static __device__ __forceinline__ float gelu_f(float x) {
    float z = 0.7978845608028654f * (x + 0.044715f * x * x * x);
    float e = __expf(2.0f * z);
    float t = 1.0f - 2.0f / (e + 1.0f);   // tanh(z)
    return 0.5f * x * (1.0f + t);
}
// async global->LDS DMA, 16B per lane; LDS dest = base + lane*16 (wave-uniform base)
static __device__ __forceinline__ void async_load16(const void* g, void* l) {
    __builtin_amdgcn_global_load_lds(
        (const __attribute__((address_space(1))) unsigned int*)g,
        (__attribute__((address_space(3))) unsigned int*)l, 16, 0, 0);
}

// ---------------- combined prep kernel ----------------
// Layouts (INTERLEAVED complex): Bu col index k = d*512 + 2p + comp.
// Bmat[k][h] (1024x256 bf16): B_bar with rows permuted to match.
// B3[d][h][k'] (2x256x512 bf16): k'=2p+comp -> comp? -C_imag[h][p] : C_real[h][p]
// LbarWS[d*256+p] = (Lbar_r, Lbar_i) fp32.
__global__ void prep_kernel(const float* fLr, const float* fIm, const float* fLd,
                            const float* fBr, const float* fBi,
                            const float* fCr, const float* fCi,
                            const float* bLr, const float* bIm, const float* bLd,
                            const float* bBr, const float* bBi,
                            const float* bCr, const float* bCi,
                            unsigned short* Bmat, unsigned short* B3, float2* LbarWS) {
    int gid = blockIdx.x * 256 + threadIdx.x;
    if (gid < 262144) {
        // Bmat
        int k = gid >> 8, h = gid & 255;
        int d = k >> 9, pc = k & 511, p = pc >> 1, comp = pc & 1;
        const float* LR = d ? bLr : fLr;
        const float* IM = d ? bIm : fIm;
        const float* LD = d ? bLd : fLd;
        const float* BR = d ? bBr : fBr;
        const float* BI = d ? bBi : fBi;
        float Lr = -expf(LR[p]);
        float Li = IM[p];
        float Delta = expf(LD[p]);
        float ea = expf(Lr * Delta);
        float bd = Li * Delta;
        float Lbr = ea * cosf(bd);
        float Lbi = ea * sinf(bd);
        float denom = fmaxf(Lr * Lr + Li * Li, 1e-12f);
        float ivr = Lr / denom, ivi = -Li / denom;
        float dr = Lbr - 1.0f, di = Lbi;
        float cr = ivr * dr - ivi * di;
        float ci = ivr * di + ivi * dr;
        float br = BR[p * 256 + h], bi = BI[p * 256 + h];
        float val = comp ? (cr * bi + ci * br) : (cr * br - ci * bi);
        Bmat[gid] = f2bf(val);
    } else if (gid < 524288) {
        int g2 = gid - 262144;
        int d = g2 >> 17;
        int rem = g2 & 131071;
        int h = rem >> 9;
        int kk = rem & 511;
        int p = kk >> 1, comp = kk & 1;
        const float* CR = d ? bCr : fCr;
        const float* CI = d ? bCi : fCi;
        float val = comp ? -CI[h * 256 + p] : CR[h * 256 + p];
        B3[g2] = f2bf(val);
    } else if (gid < 524800) {
        int g2 = gid - 524288;         // 0..511
        int d = g2 >> 8, p = g2 & 255;
        const float* LR = d ? bLr : fLr;
        const float* IM = d ? bIm : fIm;
        const float* LD = d ? bLd : fLd;
        float Lr = -expf(LR[p]); float Li = IM[p]; float Delta = expf(LD[p]);
        float ea = expf(Lr * Delta); float bd = Li * Delta;
        LbarWS[g2] = make_float2(ea * cosf(bd), ea * sinf(bd));
    }
}

// x (fp32) -> xbf (bf16)
__global__ void xcast_kernel(const float4* __restrict__ x4, ushort4* __restrict__ xb) {
    int gid = blockIdx.x * 256 + threadIdx.x;  // 0..2097151
    float4 v = x4[gid];
    ushort4 o;
    o.x = f2bf(v.x); o.y = f2bf(v.y); o.z = f2bf(v.z); o.w = f2bf(v.w);
    xb[gid] = o;
}

// ---------------- K1: Bu = xbf(32768x256) @ Bmat(1024x256)^T -> Bu bf16 (32768x1024) ----------------
__global__ __launch_bounds__(512) void k1_gemm(const unsigned short* __restrict__ A,
                                               const unsigned short* __restrict__ Bm,
                                               unsigned short* __restrict__ Bu) {
    __shared__ unsigned short As[128 * 64];   // unpadded: required by global_load_lds lane mapping
    __shared__ unsigned short Bs[128 * 64];
    int tid = threadIdx.x;
    int lane = tid & 63, wv = tid >> 6;
    int wm = (wv >> 1) * 32, wn = (wv & 1) * 64;
    int Mb = blockIdx.x * 128, Nb = blockIdx.y * 128;
    int lr = lane >> 3;            // row within 8-row chunk
    int lc = (lane & 7) * 8;       // col offset in shorts (16B per lane)
    f32x4 acc[2][4];
#pragma unroll
    for (int i = 0; i < 2; i++)
#pragma unroll
        for (int j = 0; j < 4; j++) acc[i][j] = (f32x4){0.f, 0.f, 0.f, 0.f};
    int mrow = lane & 15, quad = lane >> 4;
    for (int kb = 0; kb < 256; kb += 64) {
#pragma unroll
        for (int ch = wv; ch < 16; ch += 8) {
            int r = ch * 8 + lr;
            async_load16(A  + (size_t)(Mb + r) * 256 + kb + lc, (char*)As + ch * 1024);
            async_load16(Bm + (size_t)(Nb + r) * 256 + kb + lc, (char*)Bs + ch * 1024);
        }
        __syncthreads();
#pragma unroll
        for (int kk = 0; kk < 64; kk += 32) {
            bf16x8 af[2], bfr[4];
#pragma unroll
            for (int i = 0; i < 2; i++) af[i] = *(const bf16x8*)&As[(wm + 16 * i + mrow) * 64 + kk + quad * 8];
#pragma unroll
            for (int j = 0; j < 4; j++) bfr[j] = *(const bf16x8*)&Bs[(wn + 16 * j + mrow) * 64 + kk + quad * 8];
#pragma unroll
            for (int i = 0; i < 2; i++)
#pragma unroll
                for (int j = 0; j < 4; j++)
                    acc[i][j] = __builtin_amdgcn_mfma_f32_16x16x32_bf16(af[i], bfr[j], acc[i][j], 0, 0, 0);
        }
        __syncthreads();
    }
#pragma unroll
    for (int i = 0; i < 2; i++)
#pragma unroll
        for (int j = 0; j < 4; j++)
#pragma unroll
            for (int r = 0; r < 4; r++) {
                int row = Mb + wm + 16 * i + quad * 4 + r;
                int col = Nb + wn + 16 * j + mrow;
                Bu[(size_t)row * 1024 + col] = f2bf(acc[i][j][r]);
            }
}

// ---------------- scan pass 1: per-chunk carries ----------------
// chain = (dir d, batch b, p). Interleaved layout: uint at [row*512 + d*256 + p]
// holds (real=lo16, imag=hi16). fwd: ascending; bwd: descending (gives re-flipped states).
__global__ void scan_carry_kernel(const unsigned int* __restrict__ XSu,
                                  const float2* __restrict__ Lbar,
                                  float2* __restrict__ carry) {
    int c = blockIdx.x, b = blockIdx.y, d = blockIdx.z;
    int p = threadIdx.x;
    float2 A = Lbar[d * 256 + p];
    float sr = 0.f, si = 0.f;
    size_t base = (size_t)b * L_DIM * 512 + d * 256 + p;
    if (d == 0) {
#pragma unroll 8
        for (int t = 0; t < LC; t++) {
            unsigned int v = XSu[base + (size_t)(c * LC + t) * 512];
            float zr = bf2f(v & 0xffffu), zi = bf2f(v >> 16);
            float nr = A.x * sr - A.y * si + zr;
            float ni = A.x * si + A.y * sr + zi;
            sr = nr; si = ni;
        }
    } else {
#pragma unroll 8
        for (int t = LC - 1; t >= 0; t--) {
            unsigned int v = XSu[base + (size_t)(c * LC + t) * 512];
            float zr = bf2f(v & 0xffffu), zi = bf2f(v >> 16);
            float nr = A.x * sr - A.y * si + zr;
            float ni = A.x * si + A.y * sr + zi;
            sr = nr; si = ni;
        }
    }
    carry[((d * 4 + b) * NC + c) * 256 + p] = make_float2(sr, si);
}

// ---------------- scan pass 2: combine carries, rescan chunk, write xs in-place ----------------
__global__ void scan_fix_kernel(unsigned int* __restrict__ XSu,
                                const float2* __restrict__ Lbar,
                                const float2* __restrict__ carry) {
    int c = blockIdx.x, b = blockIdx.y, d = blockIdx.z;
    int p = threadIdx.x;
    float2 A = Lbar[d * 256 + p];
    float ar = A.x, ai = A.y;
    float a128r = ar, a128i = ai;
#pragma unroll
    for (int k = 0; k < 7; k++) {  // A^(2^7) = A^128
        float nr = a128r * a128r - a128i * a128i;
        float ni = 2.f * a128r * a128i;
        a128r = nr; a128i = ni;
    }
    float sr = 0.f, si = 0.f;
    const float2* cb = carry + ((size_t)(d * 4 + b) * NC) * 256 + p;
    size_t base = (size_t)b * L_DIM * 512 + d * 256 + p;
    if (d == 0) {
        for (int j = 0; j < c; j++) {
            float2 cj = cb[(size_t)j * 256];
            float nr = a128r * sr - a128i * si + cj.x;
            float ni = a128r * si + a128i * sr + cj.y;
            sr = nr; si = ni;
        }
#pragma unroll 8
        for (int t = 0; t < LC; t++) {
            size_t idx = base + (size_t)(c * LC + t) * 512;
            unsigned int v = XSu[idx];
            float zr = bf2f(v & 0xffffu), zi = bf2f(v >> 16);
            float nr = ar * sr - ai * si + zr;
            float ni = ar * si + ai * sr + zi;
            sr = nr; si = ni;
            XSu[idx] = (unsigned int)f2bf(sr) | ((unsigned int)f2bf(si) << 16);
        }
    } else {
        for (int j = NC - 1; j > c; j--) {
            float2 cj = cb[(size_t)j * 256];
            float nr = a128r * sr - a128i * si + cj.x;
            float ni = a128r * si + a128i * sr + cj.y;
            sr = nr; si = ni;
        }
#pragma unroll 8
        for (int t = LC - 1; t >= 0; t--) {
            size_t idx = base + (size_t)(c * LC + t) * 512;
            unsigned int v = XSu[idx];
            float zr = bf2f(v & 0xffffu), zi = bf2f(v >> 16);
            float nr = ar * sr - ai * si + zr;
            float ni = ar * si + ai * sr + zi;
            sr = nr; si = ni;
            XSu[idx] = (unsigned int)f2bf(sr) | ((unsigned int)f2bf(si) << 16);
        }
    }
}

// ---------------- K3: out = gelu(xs_f·Cf + Df*x) + gelu(W·Cb + Db*x) ----------------
__global__ __launch_bounds__(512) void k3_gemm(const unsigned short* __restrict__ XS,
                                               const unsigned short* __restrict__ B3,
                                               const float* __restrict__ x,
                                               const float* __restrict__ Df,
                                               const float* __restrict__ Db,
                                               float* __restrict__ out) {
    __shared__ unsigned short As[128 * 64];
    __shared__ unsigned short Bs[128 * 64];
    int tid = threadIdx.x;
    int lane = tid & 63, wv = tid >> 6;
    int wm = (wv >> 1) * 32, wn = (wv & 1) * 64;
    int Mb = blockIdx.x * 128, Hb = blockIdx.y * 128;
    int lr = lane >> 3;
    int lc = (lane & 7) * 8;
    f32x4 accf[2][4], accb[2][4];
#pragma unroll
    for (int i = 0; i < 2; i++)
#pragma unroll
        for (int j = 0; j < 4; j++) {
            accf[i][j] = (f32x4){0.f, 0.f, 0.f, 0.f};
            accb[i][j] = (f32x4){0.f, 0.f, 0.f, 0.f};
        }
    int mrow = lane & 15, quad = lane >> 4;
    for (int kb = 0; kb < 1024; kb += 64) {
        const unsigned short* Bh = B3 + (size_t)(kb >> 9) * 131072;
        int bcol = kb & 511;
#pragma unroll
        for (int ch = wv; ch < 16; ch += 8) {
            int r = ch * 8 + lr;
            async_load16(XS + (size_t)(Mb + r) * 1024 + kb + lc, (char*)As + ch * 1024);
            async_load16(Bh + (size_t)(Hb + r) * 512 + bcol + lc, (char*)Bs + ch * 1024);
        }
        __syncthreads();
        f32x4 (*acc)[4] = (kb & 512) ? accb : accf;
#pragma unroll
        for (int kk = 0; kk < 64; kk += 32) {
            bf16x8 af[2], bfr[4];
#pragma unroll
            for (int i = 0; i < 2; i++) af[i] = *(const bf16x8*)&As[(wm + 16 * i + mrow) * 64 + kk + quad * 8];
#pragma unroll
            for (int j = 0; j < 4; j++) bfr[j] = *(const bf16x8*)&Bs[(wn + 16 * j + mrow) * 64 + kk + quad * 8];
#pragma unroll
            for (int i = 0; i < 2; i++)
#pragma unroll
                for (int j = 0; j < 4; j++)
                    acc[i][j] = __builtin_amdgcn_mfma_f32_16x16x32_bf16(af[i], bfr[j], acc[i][j], 0, 0, 0);
        }
        __syncthreads();
    }
#pragma unroll
    for (int i = 0; i < 2; i++)
#pragma unroll
        for (int j = 0; j < 4; j++) {
            int h = Hb + wn + 16 * j + mrow;
            float df = Df[h], db = Db[h];
#pragma unroll
            for (int r = 0; r < 4; r++) {
                int row = Mb + wm + 16 * i + quad * 4 + r;
                float xv = x[(size_t)row * 256 + h];
                float yf = accf[i][j][r] + df * xv;
                float yb = accb[i][j][r] + db * xv;
                out[(size_t)row * 256 + h] = gelu_f(yf) + gelu_f(yb);
            }
        }
}

// ---------------- launcher ----------------
extern "C" void kernel_launch(void* const* d_in, const int* in_sizes, int n_in,
                              void* d_out, int out_size, void* d_ws, size_t ws_size,
                              hipStream_t stream) {
    const float* x   = (const float*)d_in[0];
    const float* fLr = (const float*)d_in[1];
    const float* fIm = (const float*)d_in[2];
    const float* fLd = (const float*)d_in[3];
    const float* fBr = (const float*)d_in[4];
    const float* fBi = (const float*)d_in[5];
    const float* fCr = (const float*)d_in[6];
    const float* fCi = (const float*)d_in[7];
    const float* fD  = (const float*)d_in[8];
    const float* bLr = (const float*)d_in[9];
    const float* bIm = (const float*)d_in[10];
    const float* bLd = (const float*)d_in[11];
    const float* bBr = (const float*)d_in[12];
    const float* bBi = (const float*)d_in[13];
    const float* bCr = (const float*)d_in[14];
    const float* bCi = (const float*)d_in[15];
    const float* bD  = (const float*)d_in[16];
    float* out = (float*)d_out;

    char* ws = (char*)d_ws;
    unsigned short* xbf  = (unsigned short*)(ws);                               // 16 MiB
    unsigned short* Bu   = (unsigned short*)(ws + 16777216);                    // 64 MiB (Bu, then xs in-place)
    unsigned short* Bmat = (unsigned short*)(ws + 16777216 + 67108864);         // 512 KiB
    unsigned short* B3   = (unsigned short*)(ws + 16777216 + 67108864 + 524288);// 512 KiB
    float2* LbarWS = (float2*)(ws + 16777216 + 67108864 + 1048576);             // 4 KiB
    float2* carry  = (float2*)(ws + 16777216 + 67108864 + 1048576 + 4096);      // 1 MiB

    prep_kernel<<<2050, 256, 0, stream>>>(fLr, fIm, fLd, fBr, fBi, fCr, fCi,
                                          bLr, bIm, bLd, bBr, bBi, bCr, bCi,
                                          Bmat, B3, LbarWS);
    xcast_kernel<<<8192, 256, 0, stream>>>((const float4*)x, (ushort4*)xbf);
    k1_gemm<<<dim3(256, 8), 512, 0, stream>>>(xbf, Bmat, Bu);
    scan_carry_kernel<<<dim3(NC, 4, 2), 256, 0, stream>>>((const unsigned int*)Bu, LbarWS, carry);
    scan_fix_kernel<<<dim3(NC, 4, 2), 256, 0, stream>>>((unsigned int*)Bu, LbarWS, carry);
    k3_gemm<<<dim3(256, 2), 512, 0, stream>>>(Bu, B3, x, fD, bD, out);
}

// Round 3
// 235.461 us; speedup vs baseline: 1.0915x; 1.0915x over previous
//
#include <hip/hip_runtime.h>
#include <math.h>

#define B_DIM 4
#define L_DIM 8192
#define H_DIM 256
#define P_DIM 256
#define M_DIM (B_DIM * L_DIM)   // 32768 rows (b,l) flattened
#define NC 64                   // scan chunks per chain
#define LC 128                  // chunk length (NC*LC = L)

typedef __attribute__((ext_vector_type(8))) short bf16x8;
typedef __attribute__((ext_vector_type(4))) float f32x4;

static __device__ __forceinline__ float bf2f(unsigned int u) {
    union { unsigned int i; float f; } v; v.i = u << 16; return v.f;
}
static __device__ __forceinline__ unsigned short f2bf(float f) {
    union { float f; unsigned int i; } v; v.f = f;
    unsigned int r = v.i + 0x7FFFu + ((v.i >> 16) & 1u);
    return (unsigned short)(r >> 16);
}
// tanh-form GELU; |gelu_tanh - gelu_erf| <= ~0.003 absolute, far under threshold
static __device__ __forceinline__ float gelu_f(float x) {
    float z = 0.7978845608028654f * (x + 0.044715f * x * x * x);
    float e = __expf(2.0f * z);
    float t = 1.0f - 2.0f / (e + 1.0f);   // tanh(z)
    return 0.5f * x * (1.0f + t);
}
// async global->LDS DMA, 16B per lane; LDS dest = base + lane*16 (wave-uniform base)
static __device__ __forceinline__ void async_load16(const void* g, void* l) {
    __builtin_amdgcn_global_load_lds(
        (const __attribute__((address_space(1))) unsigned int*)g,
        (__attribute__((address_space(3))) unsigned int*)l, 16, 0, 0);
}

// ---------------- combined prep kernel ----------------
// Layouts (INTERLEAVED complex): Bu col index k = d*512 + 2p + comp.
// Bmat[k][h] (1024x256 bf16): B_bar with rows permuted to match.
// B3[d][h][k'] (2x256x512 bf16): k'=2p+comp -> comp? -C_imag[h][p] : C_real[h][p]
// LbarWS[d*256+p] = (Lbar_r, Lbar_i) fp32.
__global__ void prep_kernel(const float* fLr, const float* fIm, const float* fLd,
                            const float* fBr, const float* fBi,
                            const float* fCr, const float* fCi,
                            const float* bLr, const float* bIm, const float* bLd,
                            const float* bBr, const float* bBi,
                            const float* bCr, const float* bCi,
                            unsigned short* Bmat, unsigned short* B3, float2* LbarWS) {
    int gid = blockIdx.x * 256 + threadIdx.x;
    if (gid < 262144) {
        // Bmat
        int k = gid >> 8, h = gid & 255;
        int d = k >> 9, pc = k & 511, p = pc >> 1, comp = pc & 1;
        const float* LR = d ? bLr : fLr;
        const float* IM = d ? bIm : fIm;
        const float* LD = d ? bLd : fLd;
        const float* BR = d ? bBr : fBr;
        const float* BI = d ? bBi : fBi;
        float Lr = -expf(LR[p]);
        float Li = IM[p];
        float Delta = expf(LD[p]);
        float ea = expf(Lr * Delta);
        float bd = Li * Delta;
        float Lbr = ea * cosf(bd);
        float Lbi = ea * sinf(bd);
        float denom = fmaxf(Lr * Lr + Li * Li, 1e-12f);
        float ivr = Lr / denom, ivi = -Li / denom;
        float dr = Lbr - 1.0f, di = Lbi;
        float cr = ivr * dr - ivi * di;
        float ci = ivr * di + ivi * dr;
        float br = BR[p * 256 + h], bi = BI[p * 256 + h];
        float val = comp ? (cr * bi + ci * br) : (cr * br - ci * bi);
        Bmat[gid] = f2bf(val);
    } else if (gid < 524288) {
        int g2 = gid - 262144;
        int d = g2 >> 17;
        int rem = g2 & 131071;
        int h = rem >> 9;
        int kk = rem & 511;
        int p = kk >> 1, comp = kk & 1;
        const float* CR = d ? bCr : fCr;
        const float* CI = d ? bCi : fCi;
        float val = comp ? -CI[h * 256 + p] : CR[h * 256 + p];
        B3[g2] = f2bf(val);
    } else if (gid < 524800) {
        int g2 = gid - 524288;         // 0..511
        int d = g2 >> 8, p = g2 & 255;
        const float* LR = d ? bLr : fLr;
        const float* IM = d ? bIm : fIm;
        const float* LD = d ? bLd : fLd;
        float Lr = -expf(LR[p]); float Li = IM[p]; float Delta = expf(LD[p]);
        float ea = expf(Lr * Delta); float bd = Li * Delta;
        LbarWS[g2] = make_float2(ea * cosf(bd), ea * sinf(bd));
    }
}

// x (fp32) -> xbf (bf16)
__global__ void xcast_kernel(const float4* __restrict__ x4, ushort4* __restrict__ xb) {
    int gid = blockIdx.x * 256 + threadIdx.x;  // 0..2097151
    float4 v = x4[gid];
    ushort4 o;
    o.x = f2bf(v.x); o.y = f2bf(v.y); o.z = f2bf(v.z); o.w = f2bf(v.w);
    xb[gid] = o;
}

// ---------------- K1: Bu = xbf(32768x256) @ Bmat(1024x256)^T -> Bu bf16 (32768x1024) ----------------
// LDS tiles use XOR-swizzled chunk layout: 16B chunk q of row r lives at physical
// chunk (q ^ (r&7)). Applied at DMA (lane fetches the matching global chunk) and
// at fragment read. Rows of a quad then span all 32 banks (2-way only = free).
// Epilogue: C tile -> LDS -> coalesced Bu store + fused per-chunk scan carries.
__global__ __launch_bounds__(512) void k1_gemm(const unsigned short* __restrict__ A,
                                               const unsigned short* __restrict__ Bm,
                                               unsigned short* __restrict__ Bu,
                                               const float2* __restrict__ Lbar,
                                               float2* __restrict__ carry) {
    __shared__ unsigned short SH[16384];   // 32 KB: As=SH[0:8192], Bs=SH[8192:]; Cs overlays all
    __shared__ float2 Sbuf[64];
    int tid = threadIdx.x;
    int lane = tid & 63, wv = tid >> 6;
    int wm = (wv >> 1) * 32, wn = (wv & 1) * 64;
    int Mb = blockIdx.x * 128, Nb = blockIdx.y * 128;
    int lr = lane >> 3;                 // row within 8-row chunk group
    int swz = ((lane & 7) ^ lr) * 8;    // swizzled source chunk (in shorts)
    f32x4 acc[2][4];
#pragma unroll
    for (int i = 0; i < 2; i++)
#pragma unroll
        for (int j = 0; j < 4; j++) acc[i][j] = (f32x4){0.f, 0.f, 0.f, 0.f};
    int mrow = lane & 15, quad = lane >> 4;
    for (int kb = 0; kb < 256; kb += 64) {
#pragma unroll
        for (int ch = wv; ch < 16; ch += 8) {
            int r = ch * 8 + lr;
            async_load16(A  + (size_t)(Mb + r) * 256 + kb + swz, (char*)SH + ch * 1024);
            async_load16(Bm + (size_t)(Nb + r) * 256 + kb + swz, (char*)SH + 16384 + ch * 1024);
        }
        __syncthreads();
#pragma unroll
        for (int kk = 0; kk < 64; kk += 32) {
            bf16x8 af[2], bfr[4];
#pragma unroll
            for (int i = 0; i < 2; i++) {
                int rr = wm + 16 * i + mrow;
                af[i] = *(const bf16x8*)&SH[rr * 64 + ((((kk >> 3) + quad) ^ (rr & 7)) << 3)];
            }
#pragma unroll
            for (int j = 0; j < 4; j++) {
                int rr = wn + 16 * j + mrow;
                bfr[j] = *(const bf16x8*)&SH[8192 + rr * 64 + ((((kk >> 3) + quad) ^ (rr & 7)) << 3)];
            }
#pragma unroll
            for (int i = 0; i < 2; i++)
#pragma unroll
                for (int j = 0; j < 4; j++)
                    acc[i][j] = __builtin_amdgcn_mfma_f32_16x16x32_bf16(af[i], bfr[j], acc[i][j], 0, 0, 0);
        }
        __syncthreads();
    }
    // ---- epilogue: C tile (128x128 bf16) into LDS ----
    unsigned short* Cs = SH;
#pragma unroll
    for (int i = 0; i < 2; i++)
#pragma unroll
        for (int j = 0; j < 4; j++)
#pragma unroll
            for (int r = 0; r < 4; r++) {
                int row = wm + 16 * i + quad * 4 + r;
                int col = wn + 16 * j + mrow;
                Cs[row * 128 + col] = f2bf(acc[i][j][r]);
            }
    __syncthreads();
    // coalesced Cs -> Bu (uint4 per thread, 4 iters)
#pragma unroll
    for (int it = 0; it < 4; it++) {
        int o = tid * 16 + it * 8192;       // byte offset in Cs
        int row = o >> 8, colb = o & 255;
        uint4 v = *(const uint4*)((const char*)Cs + o);
        *(uint4*)((char*)Bu + (size_t)(Mb + row) * 2048 + (size_t)Nb * 2 + colb) = v;
    }
    // fused per-chunk scan carry: this block is chunk c of batch b, 64 complex chains.
    int d = Nb >> 9;
    int b = Mb >> 13;
    int c = (Mb >> 7) & 63;
    float sr = 0.f, si = 0.f;
    float2 A2 = make_float2(0.f, 0.f);
    int p = 0;
    if (tid < 128) {
        int j = tid & 63, half = tid >> 6;
        p = ((Nb & 511) >> 1) + j;
        A2 = Lbar[d * 256 + p];
        const unsigned int* C32 = (const unsigned int*)Cs;
        int r0 = half * 64;
        if (d == 0) {
            for (int t = 0; t < 64; t++) {
                unsigned int v = C32[(r0 + t) * 64 + j];
                float zr = bf2f(v & 0xffffu), zi = bf2f(v >> 16);
                float nr = A2.x * sr - A2.y * si + zr;
                float ni = A2.x * si + A2.y * sr + zi;
                sr = nr; si = ni;
            }
        } else {
            for (int t = 63; t >= 0; t--) {
                unsigned int v = C32[(r0 + t) * 64 + j];
                float zr = bf2f(v & 0xffffu), zi = bf2f(v >> 16);
                float nr = A2.x * sr - A2.y * si + zr;
                float ni = A2.x * si + A2.y * sr + zi;
                sr = nr; si = ni;
            }
        }
        if (half == 1) Sbuf[j] = make_float2(sr, si);
    }
    __syncthreads();
    if (tid < 64) {
        float2 S1 = Sbuf[tid];
        float a64r = A2.x, a64i = A2.y;
#pragma unroll
        for (int k = 0; k < 6; k++) {  // A^(2^6) = A^64
            float nr = a64r * a64r - a64i * a64i;
            float ni = 2.f * a64r * a64i;
            a64r = nr; a64i = ni;
        }
        float cr, ci;
        if (d == 0) {   // carry = A^64 * S0 + S1
            cr = a64r * sr - a64i * si + S1.x;
            ci = a64r * si + a64i * sr + S1.y;
        } else {        // carry = S0 + A^64 * S1
            cr = sr + a64r * S1.x - a64i * S1.y;
            ci = si + a64r * S1.y + a64i * S1.x;
        }
        carry[((size_t)(d * 4 + b) * NC + c) * 256 + p] = make_float2(cr, ci);
    }
}

// ---------------- scan pass 2: combine carries, rescan chunk, write xs in-place ----------------
__global__ void scan_fix_kernel(unsigned int* __restrict__ XSu,
                                const float2* __restrict__ Lbar,
                                const float2* __restrict__ carry) {
    int c = blockIdx.x, b = blockIdx.y, d = blockIdx.z;
    int p = threadIdx.x;
    float2 A = Lbar[d * 256 + p];
    float ar = A.x, ai = A.y;
    float a128r = ar, a128i = ai;
#pragma unroll
    for (int k = 0; k < 7; k++) {  // A^(2^7) = A^128
        float nr = a128r * a128r - a128i * a128i;
        float ni = 2.f * a128r * a128i;
        a128r = nr; a128i = ni;
    }
    float sr = 0.f, si = 0.f;
    const float2* cb = carry + ((size_t)(d * 4 + b) * NC) * 256 + p;
    size_t base = (size_t)b * L_DIM * 512 + d * 256 + p;
    if (d == 0) {
        for (int j = 0; j < c; j++) {
            float2 cj = cb[(size_t)j * 256];
            float nr = a128r * sr - a128i * si + cj.x;
            float ni = a128r * si + a128i * sr + cj.y;
            sr = nr; si = ni;
        }
#pragma unroll 8
        for (int t = 0; t < LC; t++) {
            size_t idx = base + (size_t)(c * LC + t) * 512;
            unsigned int v = XSu[idx];
            float zr = bf2f(v & 0xffffu), zi = bf2f(v >> 16);
            float nr = ar * sr - ai * si + zr;
            float ni = ar * si + ai * sr + zi;
            sr = nr; si = ni;
            XSu[idx] = (unsigned int)f2bf(sr) | ((unsigned int)f2bf(si) << 16);
        }
    } else {
        for (int j = NC - 1; j > c; j--) {
            float2 cj = cb[(size_t)j * 256];
            float nr = a128r * sr - a128i * si + cj.x;
            float ni = a128r * si + a128i * sr + cj.y;
            sr = nr; si = ni;
        }
#pragma unroll 8
        for (int t = LC - 1; t >= 0; t--) {
            size_t idx = base + (size_t)(c * LC + t) * 512;
            unsigned int v = XSu[idx];
            float zr = bf2f(v & 0xffffu), zi = bf2f(v >> 16);
            float nr = ar * sr - ai * si + zr;
            float ni = ar * si + ai * sr + zi;
            sr = nr; si = ni;
            XSu[idx] = (unsigned int)f2bf(sr) | ((unsigned int)f2bf(si) << 16);
        }
    }
}

// ---------------- K3: out = gelu(xs_f·Cf + Df*x) + gelu(W·Cb + Db*x) ----------------
__global__ __launch_bounds__(512) void k3_gemm(const unsigned short* __restrict__ XS,
                                               const unsigned short* __restrict__ B3,
                                               const float* __restrict__ x,
                                               const float* __restrict__ Df,
                                               const float* __restrict__ Db,
                                               float* __restrict__ out) {
    __shared__ unsigned short As[128 * 64];
    __shared__ unsigned short Bs[128 * 64];
    int tid = threadIdx.x;
    int lane = tid & 63, wv = tid >> 6;
    int wm = (wv >> 1) * 32, wn = (wv & 1) * 64;
    int Mb = blockIdx.x * 128, Hb = blockIdx.y * 128;
    int lr = lane >> 3;
    int swz = ((lane & 7) ^ lr) * 8;
    f32x4 accf[2][4], accb[2][4];
#pragma unroll
    for (int i = 0; i < 2; i++)
#pragma unroll
        for (int j = 0; j < 4; j++) {
            accf[i][j] = (f32x4){0.f, 0.f, 0.f, 0.f};
            accb[i][j] = (f32x4){0.f, 0.f, 0.f, 0.f};
        }
    int mrow = lane & 15, quad = lane >> 4;
    for (int kb = 0; kb < 1024; kb += 64) {
        const unsigned short* Bh = B3 + (size_t)(kb >> 9) * 131072;
        int bcol = kb & 511;
#pragma unroll
        for (int ch = wv; ch < 16; ch += 8) {
            int r = ch * 8 + lr;
            async_load16(XS + (size_t)(Mb + r) * 1024 + kb + swz, (char*)As + ch * 1024);
            async_load16(Bh + (size_t)(Hb + r) * 512 + bcol + swz, (char*)Bs + ch * 1024);
        }
        __syncthreads();
        f32x4 (*acc)[4] = (kb & 512) ? accb : accf;
#pragma unroll
        for (int kk = 0; kk < 64; kk += 32) {
            bf16x8 af[2], bfr[4];
#pragma unroll
            for (int i = 0; i < 2; i++) {
                int rr = wm + 16 * i + mrow;
                af[i] = *(const bf16x8*)&As[rr * 64 + ((((kk >> 3) + quad) ^ (rr & 7)) << 3)];
            }
#pragma unroll
            for (int j = 0; j < 4; j++) {
                int rr = wn + 16 * j + mrow;
                bfr[j] = *(const bf16x8*)&Bs[rr * 64 + ((((kk >> 3) + quad) ^ (rr & 7)) << 3)];
            }
#pragma unroll
            for (int i = 0; i < 2; i++)
#pragma unroll
                for (int j = 0; j < 4; j++)
                    acc[i][j] = __builtin_amdgcn_mfma_f32_16x16x32_bf16(af[i], bfr[j], acc[i][j], 0, 0, 0);
        }
        __syncthreads();
    }
#pragma unroll
    for (int i = 0; i < 2; i++)
#pragma unroll
        for (int j = 0; j < 4; j++) {
            int h = Hb + wn + 16 * j + mrow;
            float df = Df[h], db = Db[h];
#pragma unroll
            for (int r = 0; r < 4; r++) {
                int row = Mb + wm + 16 * i + quad * 4 + r;
                float xv = x[(size_t)row * 256 + h];
                float yf = accf[i][j][r] + df * xv;
                float yb = accb[i][j][r] + db * xv;
                out[(size_t)row * 256 + h] = gelu_f(yf) + gelu_f(yb);
            }
        }
}

// ---------------- launcher ----------------
extern "C" void kernel_launch(void* const* d_in, const int* in_sizes, int n_in,
                              void* d_out, int out_size, void* d_ws, size_t ws_size,
                              hipStream_t stream) {
    const float* x   = (const float*)d_in[0];
    const float* fLr = (const float*)d_in[1];
    const float* fIm = (const float*)d_in[2];
    const float* fLd = (const float*)d_in[3];
    const float* fBr = (const float*)d_in[4];
    const float* fBi = (const float*)d_in[5];
    const float* fCr = (const float*)d_in[6];
    const float* fCi = (const float*)d_in[7];
    const float* fD  = (const float*)d_in[8];
    const float* bLr = (const float*)d_in[9];
    const float* bIm = (const float*)d_in[10];
    const float* bLd = (const float*)d_in[11];
    const float* bBr = (const float*)d_in[12];
    const float* bBi = (const float*)d_in[13];
    const float* bCr = (const float*)d_in[14];
    const float* bCi = (const float*)d_in[15];
    const float* bD  = (const float*)d_in[16];
    float* out = (float*)d_out;

    char* ws = (char*)d_ws;
    unsigned short* xbf  = (unsigned short*)(ws);                               // 16 MiB
    unsigned short* Bu   = (unsigned short*)(ws + 16777216);                    // 64 MiB (Bu, then xs in-place)
    unsigned short* Bmat = (unsigned short*)(ws + 16777216 + 67108864);         // 512 KiB
    unsigned short* B3   = (unsigned short*)(ws + 16777216 + 67108864 + 524288);// 512 KiB
    float2* LbarWS = (float2*)(ws + 16777216 + 67108864 + 1048576);             // 4 KiB
    float2* carry  = (float2*)(ws + 16777216 + 67108864 + 1048576 + 4096);      // 1 MiB

    prep_kernel<<<2050, 256, 0, stream>>>(fLr, fIm, fLd, fBr, fBi, fCr, fCi,
                                          bLr, bIm, bLd, bBr, bBi, bCr, bCi,
                                          Bmat, B3, LbarWS);
    xcast_kernel<<<8192, 256, 0, stream>>>((const float4*)x, (ushort4*)xbf);
    k1_gemm<<<dim3(256, 8), 512, 0, stream>>>(xbf, Bmat, Bu, LbarWS, carry);
    scan_fix_kernel<<<dim3(NC, 4, 2), 256, 0, stream>>>((unsigned int*)Bu, LbarWS, carry);
    k3_gemm<<<dim3(256, 2), 512, 0, stream>>>(Bu, B3, x, fD, bD, out);
}

// Round 4
// 209.843 us; speedup vs baseline: 1.2248x; 1.1221x over previous
//
#include <hip/hip_runtime.h>
#include <math.h>

#define B_DIM 4
#define L_DIM 8192
#define H_DIM 256
#define P_DIM 256
#define M_DIM (B_DIM * L_DIM)   // 32768 rows (b,l) flattened
#define NC 64                   // scan chunks per chain
#define LC 128                  // chunk length (NC*LC = L)

typedef __attribute__((ext_vector_type(8))) short bf16x8;
typedef __attribute__((ext_vector_type(4))) float f32x4;

static __device__ __forceinline__ float bf2f(unsigned int u) {
    union { unsigned int i; float f; } v; v.i = u << 16; return v.f;
}
static __device__ __forceinline__ unsigned short f2bf(float f) {
    union { float f; unsigned int i; } v; v.f = f;
    unsigned int r = v.i + 0x7FFFu + ((v.i >> 16) & 1u);
    return (unsigned short)(r >> 16);
}
// tanh-form GELU; |gelu_tanh - gelu_erf| <= ~0.003 absolute, far under threshold
static __device__ __forceinline__ float gelu_f(float x) {
    float z = 0.7978845608028654f * (x + 0.044715f * x * x * x);
    float e = __expf(2.0f * z);
    float t = 1.0f - 2.0f / (e + 1.0f);   // tanh(z)
    return 0.5f * x * (1.0f + t);
}
// async global->LDS DMA, 16B per lane; LDS dest = base + lane*16 (wave-uniform base)
static __device__ __forceinline__ void async_load16(const void* g, void* l) {
    __builtin_amdgcn_global_load_lds(
        (const __attribute__((address_space(1))) unsigned int*)g,
        (__attribute__((address_space(3))) unsigned int*)l, 16, 0, 0);
}

// ---------------- combined prep kernel ----------------
// Layouts (INTERLEAVED complex): Bu col index k = d*512 + 2p + comp.
// Bmat[k][h] (1024x256 bf16): B_bar with rows permuted to match.
// B3[d][h][k'] (2x256x512 bf16): k'=2p+comp -> comp? -C_imag[h][p] : C_real[h][p]
// LbarWS[d*256+p] = (Lbar_r, Lbar_i) fp32.
__global__ void prep_kernel(const float* fLr, const float* fIm, const float* fLd,
                            const float* fBr, const float* fBi,
                            const float* fCr, const float* fCi,
                            const float* bLr, const float* bIm, const float* bLd,
                            const float* bBr, const float* bBi,
                            const float* bCr, const float* bCi,
                            unsigned short* Bmat, unsigned short* B3, float2* LbarWS) {
    int gid = blockIdx.x * 256 + threadIdx.x;
    if (gid < 262144) {
        // Bmat
        int k = gid >> 8, h = gid & 255;
        int d = k >> 9, pc = k & 511, p = pc >> 1, comp = pc & 1;
        const float* LR = d ? bLr : fLr;
        const float* IM = d ? bIm : fIm;
        const float* LD = d ? bLd : fLd;
        const float* BR = d ? bBr : fBr;
        const float* BI = d ? bBi : fBi;
        float Lr = -expf(LR[p]);
        float Li = IM[p];
        float Delta = expf(LD[p]);
        float ea = expf(Lr * Delta);
        float bd = Li * Delta;
        float Lbr = ea * cosf(bd);
        float Lbi = ea * sinf(bd);
        float denom = fmaxf(Lr * Lr + Li * Li, 1e-12f);
        float ivr = Lr / denom, ivi = -Li / denom;
        float dr = Lbr - 1.0f, di = Lbi;
        float cr = ivr * dr - ivi * di;
        float ci = ivr * di + ivi * dr;
        float br = BR[p * 256 + h], bi = BI[p * 256 + h];
        float val = comp ? (cr * bi + ci * br) : (cr * br - ci * bi);
        Bmat[gid] = f2bf(val);
    } else if (gid < 524288) {
        int g2 = gid - 262144;
        int d = g2 >> 17;
        int rem = g2 & 131071;
        int h = rem >> 9;
        int kk = rem & 511;
        int p = kk >> 1, comp = kk & 1;
        const float* CR = d ? bCr : fCr;
        const float* CI = d ? bCi : fCi;
        float val = comp ? -CI[h * 256 + p] : CR[h * 256 + p];
        B3[g2] = f2bf(val);
    } else if (gid < 524800) {
        int g2 = gid - 524288;         // 0..511
        int d = g2 >> 8, p = g2 & 255;
        const float* LR = d ? bLr : fLr;
        const float* IM = d ? bIm : fIm;
        const float* LD = d ? bLd : fLd;
        float Lr = -expf(LR[p]); float Li = IM[p]; float Delta = expf(LD[p]);
        float ea = expf(Lr * Delta); float bd = Li * Delta;
        LbarWS[g2] = make_float2(ea * cosf(bd), ea * sinf(bd));
    }
}

// x (fp32) -> xbf (bf16)
__global__ void xcast_kernel(const float4* __restrict__ x4, ushort4* __restrict__ xb) {
    int gid = blockIdx.x * 256 + threadIdx.x;  // 0..2097151
    float4 v = x4[gid];
    ushort4 o;
    o.x = f2bf(v.x); o.y = f2bf(v.y); o.z = f2bf(v.z); o.w = f2bf(v.w);
    xb[gid] = o;
}

// ---------------- K1: Bu = xbf(32768x256) @ Bmat(1024x256)^T -> Bu bf16 (32768x1024) ----------------
// LDS tiles use XOR-swizzled chunk layout: 16B chunk q of row r lives at physical
// chunk (q ^ (r&7)). Rows of a quad then span all 32 banks (2-way only = free).
// Epilogue: C tile -> LDS -> coalesced Bu store + fused per-chunk scan carries.
__global__ __launch_bounds__(512) void k1_gemm(const unsigned short* __restrict__ A,
                                               const unsigned short* __restrict__ Bm,
                                               unsigned short* __restrict__ Bu,
                                               const float2* __restrict__ Lbar,
                                               float2* __restrict__ carry) {
    __shared__ unsigned short SH[16384];   // 32 KB: As=SH[0:8192], Bs=SH[8192:]; Cs overlays all
    __shared__ float2 Sbuf[64];
    int tid = threadIdx.x;
    int lane = tid & 63, wv = tid >> 6;
    int wm = (wv >> 1) * 32, wn = (wv & 1) * 64;
    int Mb = blockIdx.x * 128, Nb = blockIdx.y * 128;
    int lr = lane >> 3;                 // row within 8-row chunk group
    int swz = ((lane & 7) ^ lr) * 8;    // swizzled source chunk (in shorts)
    f32x4 acc[2][4];
#pragma unroll
    for (int i = 0; i < 2; i++)
#pragma unroll
        for (int j = 0; j < 4; j++) acc[i][j] = (f32x4){0.f, 0.f, 0.f, 0.f};
    int mrow = lane & 15, quad = lane >> 4;
    for (int kb = 0; kb < 256; kb += 64) {
#pragma unroll
        for (int ch = wv; ch < 16; ch += 8) {
            int r = ch * 8 + lr;
            async_load16(A  + (size_t)(Mb + r) * 256 + kb + swz, (char*)SH + ch * 1024);
            async_load16(Bm + (size_t)(Nb + r) * 256 + kb + swz, (char*)SH + 16384 + ch * 1024);
        }
        __syncthreads();
#pragma unroll
        for (int kk = 0; kk < 64; kk += 32) {
            bf16x8 af[2], bfr[4];
#pragma unroll
            for (int i = 0; i < 2; i++) {
                int rr = wm + 16 * i + mrow;
                af[i] = *(const bf16x8*)&SH[rr * 64 + ((((kk >> 3) + quad) ^ (rr & 7)) << 3)];
            }
#pragma unroll
            for (int j = 0; j < 4; j++) {
                int rr = wn + 16 * j + mrow;
                bfr[j] = *(const bf16x8*)&SH[8192 + rr * 64 + ((((kk >> 3) + quad) ^ (rr & 7)) << 3)];
            }
#pragma unroll
            for (int i = 0; i < 2; i++)
#pragma unroll
                for (int j = 0; j < 4; j++)
                    acc[i][j] = __builtin_amdgcn_mfma_f32_16x16x32_bf16(af[i], bfr[j], acc[i][j], 0, 0, 0);
        }
        __syncthreads();
    }
    // ---- epilogue: C tile (128x128 bf16) into LDS ----
    unsigned short* Cs = SH;
#pragma unroll
    for (int i = 0; i < 2; i++)
#pragma unroll
        for (int j = 0; j < 4; j++)
#pragma unroll
            for (int r = 0; r < 4; r++) {
                int row = wm + 16 * i + quad * 4 + r;
                int col = wn + 16 * j + mrow;
                Cs[row * 128 + col] = f2bf(acc[i][j][r]);
            }
    __syncthreads();
    // coalesced Cs -> Bu (uint4 per thread, 4 iters)
#pragma unroll
    for (int it = 0; it < 4; it++) {
        int o = tid * 16 + it * 8192;       // byte offset in Cs
        int row = o >> 8, colb = o & 255;
        uint4 v = *(const uint4*)((const char*)Cs + o);
        *(uint4*)((char*)Bu + (size_t)(Mb + row) * 2048 + (size_t)Nb * 2 + colb) = v;
    }
    // fused per-chunk scan carry: this block is chunk c of batch b, 64 complex chains.
    int d = Nb >> 9;
    int b = Mb >> 13;
    int c = (Mb >> 7) & 63;
    float sr = 0.f, si = 0.f;
    float2 A2 = make_float2(0.f, 0.f);
    int p = 0;
    if (tid < 128) {
        int j = tid & 63, half = tid >> 6;
        p = ((Nb & 511) >> 1) + j;
        A2 = Lbar[d * 256 + p];
        const unsigned int* C32 = (const unsigned int*)Cs;
        int r0 = half * 64;
        if (d == 0) {
            for (int t = 0; t < 64; t++) {
                unsigned int v = C32[(r0 + t) * 64 + j];
                float zr = bf2f(v & 0xffffu), zi = bf2f(v >> 16);
                float nr = A2.x * sr - A2.y * si + zr;
                float ni = A2.x * si + A2.y * sr + zi;
                sr = nr; si = ni;
            }
        } else {
            for (int t = 63; t >= 0; t--) {
                unsigned int v = C32[(r0 + t) * 64 + j];
                float zr = bf2f(v & 0xffffu), zi = bf2f(v >> 16);
                float nr = A2.x * sr - A2.y * si + zr;
                float ni = A2.x * si + A2.y * sr + zi;
                sr = nr; si = ni;
            }
        }
        if (half == 1) Sbuf[j] = make_float2(sr, si);
    }
    __syncthreads();
    if (tid < 64) {
        float2 S1 = Sbuf[tid];
        float a64r = A2.x, a64i = A2.y;
#pragma unroll
        for (int k = 0; k < 6; k++) {  // A^(2^6) = A^64
            float nr = a64r * a64r - a64i * a64i;
            float ni = 2.f * a64r * a64i;
            a64r = nr; a64i = ni;
        }
        float cr, ci;
        if (d == 0) {   // carry = A^64 * S0 + S1
            cr = a64r * sr - a64i * si + S1.x;
            ci = a64r * si + a64i * sr + S1.y;
        } else {        // carry = S0 + A^64 * S1
            cr = sr + a64r * S1.x - a64i * S1.y;
            ci = si + a64r * S1.y + a64i * S1.x;
        }
        carry[((size_t)(d * 4 + b) * NC + c) * 256 + p] = make_float2(cr, ci);
    }
}

// ---------------- scan pass 2: combine carries, rescan chunk, write xs in-place ----------------
// 512 threads: d = tid>>8 (wave-uniform), p = tid&255.
__global__ __launch_bounds__(512) void scan_fix_kernel(unsigned int* __restrict__ XSu,
                                                       const float2* __restrict__ Lbar,
                                                       const float2* __restrict__ carry) {
    int c = blockIdx.x, b = blockIdx.y;
    int d = threadIdx.x >> 8;
    int p = threadIdx.x & 255;
    float2 A = Lbar[d * 256 + p];
    float ar = A.x, ai = A.y;
    float a128r = ar, a128i = ai;
#pragma unroll
    for (int k = 0; k < 7; k++) {  // A^(2^7) = A^128
        float nr = a128r * a128r - a128i * a128i;
        float ni = 2.f * a128r * a128i;
        a128r = nr; a128i = ni;
    }
    float sr = 0.f, si = 0.f;
    const float2* cb = carry + ((size_t)(d * 4 + b) * NC) * 256 + p;
    size_t base = (size_t)b * L_DIM * 512 + d * 256 + p;
    if (d == 0) {
        for (int j = 0; j < c; j++) {
            float2 cj = cb[(size_t)j * 256];
            float nr = a128r * sr - a128i * si + cj.x;
            float ni = a128r * si + a128i * sr + cj.y;
            sr = nr; si = ni;
        }
#pragma unroll 16
        for (int t = 0; t < LC; t++) {
            size_t idx = base + (size_t)(c * LC + t) * 512;
            unsigned int v = XSu[idx];
            float zr = bf2f(v & 0xffffu), zi = bf2f(v >> 16);
            float nr = ar * sr - ai * si + zr;
            float ni = ar * si + ai * sr + zi;
            sr = nr; si = ni;
            XSu[idx] = (unsigned int)f2bf(sr) | ((unsigned int)f2bf(si) << 16);
        }
    } else {
        for (int j = NC - 1; j > c; j--) {
            float2 cj = cb[(size_t)j * 256];
            float nr = a128r * sr - a128i * si + cj.x;
            float ni = a128r * si + a128i * sr + cj.y;
            sr = nr; si = ni;
        }
#pragma unroll 16
        for (int t = LC - 1; t >= 0; t--) {
            size_t idx = base + (size_t)(c * LC + t) * 512;
            unsigned int v = XSu[idx];
            float zr = bf2f(v & 0xffffu), zi = bf2f(v >> 16);
            float nr = ar * sr - ai * si + zr;
            float ni = ar * si + ai * sr + zi;
            sr = nr; si = ni;
            XSu[idx] = (unsigned int)f2bf(sr) | ((unsigned int)f2bf(si) << 16);
        }
    }
}

// ---------------- K3 half: one K=512 GEMM with statically-bound accumulator ----------------
static __device__ __forceinline__ void k3_half(const unsigned short* __restrict__ XS,
                                               const unsigned short* __restrict__ B3h,
                                               unsigned short* As, unsigned short* Bs,
                                               int Mb, int Hb, int coff,
                                               int wm, int wn, int mrow, int quad,
                                               int lr, int swz, int wv,
                                               f32x4 (&acc)[2][4]) {
    for (int kb = 0; kb < 512; kb += 64) {
#pragma unroll
        for (int ch = wv; ch < 16; ch += 8) {
            int r = ch * 8 + lr;
            async_load16(XS + (size_t)(Mb + r) * 1024 + coff + kb + swz, (char*)As + ch * 1024);
            async_load16(B3h + (size_t)(Hb + r) * 512 + kb + swz, (char*)Bs + ch * 1024);
        }
        __syncthreads();
#pragma unroll
        for (int kk = 0; kk < 64; kk += 32) {
            bf16x8 af[2], bfr[4];
#pragma unroll
            for (int i = 0; i < 2; i++) {
                int rr = wm + 16 * i + mrow;
                af[i] = *(const bf16x8*)&As[rr * 64 + ((((kk >> 3) + quad) ^ (rr & 7)) << 3)];
            }
#pragma unroll
            for (int j = 0; j < 4; j++) {
                int rr = wn + 16 * j + mrow;
                bfr[j] = *(const bf16x8*)&Bs[rr * 64 + ((((kk >> 3) + quad) ^ (rr & 7)) << 3)];
            }
#pragma unroll
            for (int i = 0; i < 2; i++)
#pragma unroll
                for (int j = 0; j < 4; j++)
                    acc[i][j] = __builtin_amdgcn_mfma_f32_16x16x32_bf16(af[i], bfr[j], acc[i][j], 0, 0, 0);
        }
        __syncthreads();
    }
}

// ---------------- K3: out = gelu(xs_f·Cf + Df*x) + gelu(W·Cb + Db*x) ----------------
__global__ __launch_bounds__(512) void k3_gemm(const unsigned short* __restrict__ XS,
                                               const unsigned short* __restrict__ B3,
                                               const unsigned short* __restrict__ xbf,
                                               const float* __restrict__ Df,
                                               const float* __restrict__ Db,
                                               float* __restrict__ out) {
    __shared__ unsigned short As[128 * 64];
    __shared__ unsigned short Bs[128 * 64];
    int tid = threadIdx.x;
    int lane = tid & 63, wv = tid >> 6;
    int wm = (wv >> 1) * 32, wn = (wv & 1) * 64;
    int Mb = blockIdx.x * 128, Hb = blockIdx.y * 128;
    int lr = lane >> 3;
    int swz = ((lane & 7) ^ lr) * 8;
    int mrow = lane & 15, quad = lane >> 4;
    f32x4 accf[2][4], accb[2][4];
#pragma unroll
    for (int i = 0; i < 2; i++)
#pragma unroll
        for (int j = 0; j < 4; j++) {
            accf[i][j] = (f32x4){0.f, 0.f, 0.f, 0.f};
            accb[i][j] = (f32x4){0.f, 0.f, 0.f, 0.f};
        }
    // forward half (k-cols 0..511), then backward half (512..1023) — statically bound accs
    k3_half(XS, B3,          As, Bs, Mb, Hb, 0,   wm, wn, mrow, quad, lr, swz, wv, accf);
    k3_half(XS, B3 + 131072, As, Bs, Mb, Hb, 512, wm, wn, mrow, quad, lr, swz, wv, accb);
#pragma unroll
    for (int i = 0; i < 2; i++)
#pragma unroll
        for (int j = 0; j < 4; j++) {
            int h = Hb + wn + 16 * j + mrow;
            float df = Df[h], db = Db[h];
#pragma unroll
            for (int r = 0; r < 4; r++) {
                int row = Mb + wm + 16 * i + quad * 4 + r;
                float xv = bf2f((unsigned int)xbf[(size_t)row * 256 + h]);
                float yf = accf[i][j][r] + df * xv;
                float yb = accb[i][j][r] + db * xv;
                out[(size_t)row * 256 + h] = gelu_f(yf) + gelu_f(yb);
            }
        }
}

// ---------------- launcher ----------------
extern "C" void kernel_launch(void* const* d_in, const int* in_sizes, int n_in,
                              void* d_out, int out_size, void* d_ws, size_t ws_size,
                              hipStream_t stream) {
    const float* x   = (const float*)d_in[0];
    const float* fLr = (const float*)d_in[1];
    const float* fIm = (const float*)d_in[2];
    const float* fLd = (const float*)d_in[3];
    const float* fBr = (const float*)d_in[4];
    const float* fBi = (const float*)d_in[5];
    const float* fCr = (const float*)d_in[6];
    const float* fCi = (const float*)d_in[7];
    const float* fD  = (const float*)d_in[8];
    const float* bLr = (const float*)d_in[9];
    const float* bIm = (const float*)d_in[10];
    const float* bLd = (const float*)d_in[11];
    const float* bBr = (const float*)d_in[12];
    const float* bBi = (const float*)d_in[13];
    const float* bCr = (const float*)d_in[14];
    const float* bCi = (const float*)d_in[15];
    const float* bD  = (const float*)d_in[16];
    float* out = (float*)d_out;

    char* ws = (char*)d_ws;
    unsigned short* xbf  = (unsigned short*)(ws);                               // 16 MiB
    unsigned short* Bu   = (unsigned short*)(ws + 16777216);                    // 64 MiB (Bu, then xs in-place)
    unsigned short* Bmat = (unsigned short*)(ws + 16777216 + 67108864);         // 512 KiB
    unsigned short* B3   = (unsigned short*)(ws + 16777216 + 67108864 + 524288);// 512 KiB
    float2* LbarWS = (float2*)(ws + 16777216 + 67108864 + 1048576);             // 4 KiB
    float2* carry  = (float2*)(ws + 16777216 + 67108864 + 1048576 + 4096);      // 1 MiB

    prep_kernel<<<2050, 256, 0, stream>>>(fLr, fIm, fLd, fBr, fBi, fCr, fCi,
                                          bLr, bIm, bLd, bBr, bBi, bCr, bCi,
                                          Bmat, B3, LbarWS);
    xcast_kernel<<<8192, 256, 0, stream>>>((const float4*)x, (ushort4*)xbf);
    k1_gemm<<<dim3(256, 8), 512, 0, stream>>>(xbf, Bmat, Bu, LbarWS, carry);
    scan_fix_kernel<<<dim3(NC, 4), 512, 0, stream>>>((unsigned int*)Bu, LbarWS, carry);
    k3_gemm<<<dim3(256, 2), 512, 0, stream>>>(Bu, B3, xbf, fD, bD, out);
}

// Round 5
// 203.473 us; speedup vs baseline: 1.2631x; 1.0313x over previous
//
#include <hip/hip_runtime.h>
#include <math.h>

#define B_DIM 4
#define L_DIM 8192
#define H_DIM 256
#define P_DIM 256
#define M_DIM (B_DIM * L_DIM)   // 32768 rows (b,l) flattened
#define NC 64                   // scan chunks per chain
#define LC 128                  // chunk length (NC*LC = L)

typedef __attribute__((ext_vector_type(8))) short bf16x8;
typedef __attribute__((ext_vector_type(4))) float f32x4;

static __device__ __forceinline__ float bf2f(unsigned int u) {
    union { unsigned int i; float f; } v; v.i = u << 16; return v.f;
}
static __device__ __forceinline__ unsigned short f2bf(float f) {
    union { float f; unsigned int i; } v; v.f = f;
    unsigned int r = v.i + 0x7FFFu + ((v.i >> 16) & 1u);
    return (unsigned short)(r >> 16);
}
// tanh-form GELU; |gelu_tanh - gelu_erf| <= ~0.003 absolute, far under threshold
static __device__ __forceinline__ float gelu_f(float x) {
    float z = 0.7978845608028654f * (x + 0.044715f * x * x * x);
    float e = __expf(2.0f * z);
    float t = 1.0f - 2.0f / (e + 1.0f);   // tanh(z)
    return 0.5f * x * (1.0f + t);
}
// async global->LDS DMA, 16B per lane; LDS dest = base + lane*16 (wave-uniform base)
static __device__ __forceinline__ void async_load16(const void* g, void* l) {
    __builtin_amdgcn_global_load_lds(
        (const __attribute__((address_space(1))) unsigned int*)g,
        (__attribute__((address_space(3))) unsigned int*)l, 16, 0, 0);
}

// ---------------- combined prep kernel ----------------
// Layouts (INTERLEAVED complex): Bu col index k = d*512 + 2p + comp.
// Bmat[k][h] (1024x256 bf16): B_bar with rows permuted to match.
// B3[d][h][k'] (2x256x512 bf16): k'=2p+comp -> comp? -C_imag[h][p] : C_real[h][p]
// LbarWS[d*256+p] = (Lbar_r, Lbar_i) fp32.
__global__ void prep_kernel(const float* fLr, const float* fIm, const float* fLd,
                            const float* fBr, const float* fBi,
                            const float* fCr, const float* fCi,
                            const float* bLr, const float* bIm, const float* bLd,
                            const float* bBr, const float* bBi,
                            const float* bCr, const float* bCi,
                            unsigned short* Bmat, unsigned short* B3, float2* LbarWS) {
    int gid = blockIdx.x * 256 + threadIdx.x;
    if (gid < 262144) {
        // Bmat
        int k = gid >> 8, h = gid & 255;
        int d = k >> 9, pc = k & 511, p = pc >> 1, comp = pc & 1;
        const float* LR = d ? bLr : fLr;
        const float* IM = d ? bIm : fIm;
        const float* LD = d ? bLd : fLd;
        const float* BR = d ? bBr : fBr;
        const float* BI = d ? bBi : fBi;
        float Lr = -expf(LR[p]);
        float Li = IM[p];
        float Delta = expf(LD[p]);
        float ea = expf(Lr * Delta);
        float bd = Li * Delta;
        float Lbr = ea * cosf(bd);
        float Lbi = ea * sinf(bd);
        float denom = fmaxf(Lr * Lr + Li * Li, 1e-12f);
        float ivr = Lr / denom, ivi = -Li / denom;
        float dr = Lbr - 1.0f, di = Lbi;
        float cr = ivr * dr - ivi * di;
        float ci = ivr * di + ivi * dr;
        float br = BR[p * 256 + h], bi = BI[p * 256 + h];
        float val = comp ? (cr * bi + ci * br) : (cr * br - ci * bi);
        Bmat[gid] = f2bf(val);
    } else if (gid < 524288) {
        int g2 = gid - 262144;
        int d = g2 >> 17;
        int rem = g2 & 131071;
        int h = rem >> 9;
        int kk = rem & 511;
        int p = kk >> 1, comp = kk & 1;
        const float* CR = d ? bCr : fCr;
        const float* CI = d ? bCi : fCi;
        float val = comp ? -CI[h * 256 + p] : CR[h * 256 + p];
        B3[g2] = f2bf(val);
    } else if (gid < 524800) {
        int g2 = gid - 524288;         // 0..511
        int d = g2 >> 8, p = g2 & 255;
        const float* LR = d ? bLr : fLr;
        const float* IM = d ? bIm : fIm;
        const float* LD = d ? bLd : fLd;
        float Lr = -expf(LR[p]); float Li = IM[p]; float Delta = expf(LD[p]);
        float ea = expf(Lr * Delta); float bd = Li * Delta;
        LbarWS[g2] = make_float2(ea * cosf(bd), ea * sinf(bd));
    }
}

// x (fp32) -> xbf (bf16)
__global__ void xcast_kernel(const float4* __restrict__ x4, ushort4* __restrict__ xb) {
    int gid = blockIdx.x * 256 + threadIdx.x;  // 0..2097151
    float4 v = x4[gid];
    ushort4 o;
    o.x = f2bf(v.x); o.y = f2bf(v.y); o.z = f2bf(v.z); o.w = f2bf(v.w);
    xb[gid] = o;
}

// ---------------- K1: Bu = xbf(32768x256) @ Bmat(1024x256)^T -> Bu bf16 (32768x1024) ----------------
// m97 geometry: 256 threads / 4 waves, 128x128 tile, wave = 64x64 quadrant (4x4 f32x4 accs),
// BK=64, XOR-swizzled LDS chunks (16B chunk q of row r at q^(r&7); 0 conflicts verified).
// Epilogue: C tile -> LDS -> coalesced Bu store + fused per-chunk scan carries.
__global__ __launch_bounds__(256, 2) void k1_gemm(const unsigned short* __restrict__ A,
                                                  const unsigned short* __restrict__ Bm,
                                                  unsigned short* __restrict__ Bu,
                                                  const float2* __restrict__ Lbar,
                                                  float2* __restrict__ carry) {
    __shared__ unsigned short SH[16384];   // 32 KB: As=SH[0:8192], Bs=SH[8192:16384]; Cs overlays all
    __shared__ float2 Sbuf[64];
    int tid = threadIdx.x;
    int lane = tid & 63, wv = tid >> 6;          // 4 waves
    int wm = (wv >> 1) * 64, wn = (wv & 1) * 64; // 64x64 quadrant
    int Mb = blockIdx.x * 128, Nb = blockIdx.y * 128;
    int lr = lane >> 3;                 // row within 8-row chunk group
    int swz = ((lane & 7) ^ lr) * 8;    // swizzled source chunk (in shorts)
    f32x4 acc[4][4];
#pragma unroll
    for (int i = 0; i < 4; i++)
#pragma unroll
        for (int j = 0; j < 4; j++) acc[i][j] = (f32x4){0.f, 0.f, 0.f, 0.f};
    int mrow = lane & 15, quad = lane >> 4;
    for (int kb = 0; kb < 256; kb += 64) {
#pragma unroll
        for (int ch = wv; ch < 16; ch += 4) {
            int r = ch * 8 + lr;
            async_load16(A  + (size_t)(Mb + r) * 256 + kb + swz, (char*)SH + ch * 1024);
            async_load16(Bm + (size_t)(Nb + r) * 256 + kb + swz, (char*)SH + 16384 + ch * 1024);
        }
        __syncthreads();
#pragma unroll
        for (int kk = 0; kk < 64; kk += 32) {
            bf16x8 af[4], bfr[4];
#pragma unroll
            for (int i = 0; i < 4; i++) {
                int rr = wm + 16 * i + mrow;
                af[i] = *(const bf16x8*)&SH[rr * 64 + ((((kk >> 3) + quad) ^ (rr & 7)) << 3)];
            }
#pragma unroll
            for (int j = 0; j < 4; j++) {
                int rr = wn + 16 * j + mrow;
                bfr[j] = *(const bf16x8*)&SH[8192 + rr * 64 + ((((kk >> 3) + quad) ^ (rr & 7)) << 3)];
            }
#pragma unroll
            for (int i = 0; i < 4; i++)
#pragma unroll
                for (int j = 0; j < 4; j++)
                    acc[i][j] = __builtin_amdgcn_mfma_f32_16x16x32_bf16(af[i], bfr[j], acc[i][j], 0, 0, 0);
        }
        __syncthreads();
    }
    // ---- epilogue: C tile (128x128 bf16) into LDS ----
    unsigned short* Cs = SH;
#pragma unroll
    for (int i = 0; i < 4; i++)
#pragma unroll
        for (int j = 0; j < 4; j++)
#pragma unroll
            for (int r = 0; r < 4; r++) {
                int row = wm + 16 * i + quad * 4 + r;
                int col = wn + 16 * j + mrow;
                Cs[row * 128 + col] = f2bf(acc[i][j][r]);
            }
    __syncthreads();
    // coalesced Cs -> Bu (uint4 per thread, 8 iters)
#pragma unroll
    for (int it = 0; it < 8; it++) {
        int o = tid * 16 + it * 4096;       // byte offset in Cs
        int row = o >> 8, colb = o & 255;
        uint4 v = *(const uint4*)((const char*)Cs + o);
        *(uint4*)((char*)Bu + (size_t)(Mb + row) * 2048 + (size_t)Nb * 2 + colb) = v;
    }
    // fused per-chunk scan carry: this block is chunk c of batch b, 64 complex chains.
    int d = Nb >> 9;
    int b = Mb >> 13;
    int c = (Mb >> 7) & 63;
    float sr = 0.f, si = 0.f;
    float2 A2 = make_float2(0.f, 0.f);
    int p = 0;
    if (tid < 128) {
        int j = tid & 63, half = tid >> 6;
        p = ((Nb & 511) >> 1) + j;
        A2 = Lbar[d * 256 + p];
        const unsigned int* C32 = (const unsigned int*)Cs;
        int r0 = half * 64;
        if (d == 0) {
            for (int t = 0; t < 64; t++) {
                unsigned int v = C32[(r0 + t) * 64 + j];
                float zr = bf2f(v & 0xffffu), zi = bf2f(v >> 16);
                float nr = A2.x * sr - A2.y * si + zr;
                float ni = A2.x * si + A2.y * sr + zi;
                sr = nr; si = ni;
            }
        } else {
            for (int t = 63; t >= 0; t--) {
                unsigned int v = C32[(r0 + t) * 64 + j];
                float zr = bf2f(v & 0xffffu), zi = bf2f(v >> 16);
                float nr = A2.x * sr - A2.y * si + zr;
                float ni = A2.x * si + A2.y * sr + zi;
                sr = nr; si = ni;
            }
        }
        if (half == 1) Sbuf[j] = make_float2(sr, si);
    }
    __syncthreads();
    if (tid < 64) {
        float2 S1 = Sbuf[tid];
        float a64r = A2.x, a64i = A2.y;
#pragma unroll
        for (int k = 0; k < 6; k++) {  // A^(2^6) = A^64
            float nr = a64r * a64r - a64i * a64i;
            float ni = 2.f * a64r * a64i;
            a64r = nr; a64i = ni;
        }
        float cr, ci;
        if (d == 0) {   // carry = A^64 * S0 + S1
            cr = a64r * sr - a64i * si + S1.x;
            ci = a64r * si + a64i * sr + S1.y;
        } else {        // carry = S0 + A^64 * S1
            cr = sr + a64r * S1.x - a64i * S1.y;
            ci = si + a64r * S1.y + a64i * S1.x;
        }
        carry[((size_t)(d * 4 + b) * NC + c) * 256 + p] = make_float2(cr, ci);
    }
}

// ---------------- scan pass 2: combine carries, rescan chunk, write xs in-place ----------------
// 512 threads: d = tid>>8 (wave-uniform), p = tid&255.
__global__ __launch_bounds__(512) void scan_fix_kernel(unsigned int* __restrict__ XSu,
                                                       const float2* __restrict__ Lbar,
                                                       const float2* __restrict__ carry) {
    int c = blockIdx.x, b = blockIdx.y;
    int d = threadIdx.x >> 8;
    int p = threadIdx.x & 255;
    float2 A = Lbar[d * 256 + p];
    float ar = A.x, ai = A.y;
    float a128r = ar, a128i = ai;
#pragma unroll
    for (int k = 0; k < 7; k++) {  // A^(2^7) = A^128
        float nr = a128r * a128r - a128i * a128i;
        float ni = 2.f * a128r * a128i;
        a128r = nr; a128i = ni;
    }
    float sr = 0.f, si = 0.f;
    const float2* cb = carry + ((size_t)(d * 4 + b) * NC) * 256 + p;
    size_t base = (size_t)b * L_DIM * 512 + d * 256 + p;
    if (d == 0) {
        for (int j = 0; j < c; j++) {
            float2 cj = cb[(size_t)j * 256];
            float nr = a128r * sr - a128i * si + cj.x;
            float ni = a128r * si + a128i * sr + cj.y;
            sr = nr; si = ni;
        }
#pragma unroll 16
        for (int t = 0; t < LC; t++) {
            size_t idx = base + (size_t)(c * LC + t) * 512;
            unsigned int v = XSu[idx];
            float zr = bf2f(v & 0xffffu), zi = bf2f(v >> 16);
            float nr = ar * sr - ai * si + zr;
            float ni = ar * si + ai * sr + zi;
            sr = nr; si = ni;
            XSu[idx] = (unsigned int)f2bf(sr) | ((unsigned int)f2bf(si) << 16);
        }
    } else {
        for (int j = NC - 1; j > c; j--) {
            float2 cj = cb[(size_t)j * 256];
            float nr = a128r * sr - a128i * si + cj.x;
            float ni = a128r * si + a128i * sr + cj.y;
            sr = nr; si = ni;
        }
#pragma unroll 16
        for (int t = LC - 1; t >= 0; t--) {
            size_t idx = base + (size_t)(c * LC + t) * 512;
            unsigned int v = XSu[idx];
            float zr = bf2f(v & 0xffffu), zi = bf2f(v >> 16);
            float nr = ar * sr - ai * si + zr;
            float ni = ar * si + ai * sr + zi;
            sr = nr; si = ni;
            XSu[idx] = (unsigned int)f2bf(sr) | ((unsigned int)f2bf(si) << 16);
        }
    }
}

// ---------------- K3 half: one K=512 GEMM with statically-bound accumulator ----------------
static __device__ __forceinline__ void k3_half(const unsigned short* __restrict__ XS,
                                               const unsigned short* __restrict__ B3h,
                                               unsigned short* As, unsigned short* Bs,
                                               int Mb, int Hb, int coff,
                                               int wm, int wn, int mrow, int quad,
                                               int lr, int swz, int wv,
                                               f32x4 (&acc)[4][4]) {
    for (int kb = 0; kb < 512; kb += 64) {
#pragma unroll
        for (int ch = wv; ch < 16; ch += 4) {
            int r = ch * 8 + lr;
            async_load16(XS + (size_t)(Mb + r) * 1024 + coff + kb + swz, (char*)As + ch * 1024);
            async_load16(B3h + (size_t)(Hb + r) * 512 + kb + swz, (char*)Bs + ch * 1024);
        }
        __syncthreads();
#pragma unroll
        for (int kk = 0; kk < 64; kk += 32) {
            bf16x8 af[4], bfr[4];
#pragma unroll
            for (int i = 0; i < 4; i++) {
                int rr = wm + 16 * i + mrow;
                af[i] = *(const bf16x8*)&As[rr * 64 + ((((kk >> 3) + quad) ^ (rr & 7)) << 3)];
            }
#pragma unroll
            for (int j = 0; j < 4; j++) {
                int rr = wn + 16 * j + mrow;
                bfr[j] = *(const bf16x8*)&Bs[rr * 64 + ((((kk >> 3) + quad) ^ (rr & 7)) << 3)];
            }
#pragma unroll
            for (int i = 0; i < 4; i++)
#pragma unroll
                for (int j = 0; j < 4; j++)
                    acc[i][j] = __builtin_amdgcn_mfma_f32_16x16x32_bf16(af[i], bfr[j], acc[i][j], 0, 0, 0);
        }
        __syncthreads();
    }
}

// ---------------- K3: out = gelu(xs_f·Cf + Df*x) + gelu(W·Cb + Db*x) ----------------
__global__ __launch_bounds__(256, 2) void k3_gemm(const unsigned short* __restrict__ XS,
                                                  const unsigned short* __restrict__ B3,
                                                  const unsigned short* __restrict__ xbf,
                                                  const float* __restrict__ Df,
                                                  const float* __restrict__ Db,
                                                  float* __restrict__ out) {
    __shared__ unsigned short As[128 * 64];
    __shared__ unsigned short Bs[128 * 64];
    int tid = threadIdx.x;
    int lane = tid & 63, wv = tid >> 6;          // 4 waves
    int wm = (wv >> 1) * 64, wn = (wv & 1) * 64; // 64x64 quadrant
    int Mb = blockIdx.x * 128, Hb = blockIdx.y * 128;
    int lr = lane >> 3;
    int swz = ((lane & 7) ^ lr) * 8;
    int mrow = lane & 15, quad = lane >> 4;
    f32x4 accf[4][4], accb[4][4];
#pragma unroll
    for (int i = 0; i < 4; i++)
#pragma unroll
        for (int j = 0; j < 4; j++) {
            accf[i][j] = (f32x4){0.f, 0.f, 0.f, 0.f};
            accb[i][j] = (f32x4){0.f, 0.f, 0.f, 0.f};
        }
    // forward half (k-cols 0..511), then backward half (512..1023) — statically bound accs
    k3_half(XS, B3,          As, Bs, Mb, Hb, 0,   wm, wn, mrow, quad, lr, swz, wv, accf);
    k3_half(XS, B3 + 131072, As, Bs, Mb, Hb, 512, wm, wn, mrow, quad, lr, swz, wv, accb);
#pragma unroll
    for (int i = 0; i < 4; i++)
#pragma unroll
        for (int j = 0; j < 4; j++) {
            int h = Hb + wn + 16 * j + mrow;
            float df = Df[h], db = Db[h];
#pragma unroll
            for (int r = 0; r < 4; r++) {
                int row = Mb + wm + 16 * i + quad * 4 + r;
                float xv = bf2f((unsigned int)xbf[(size_t)row * 256 + h]);
                float yf = accf[i][j][r] + df * xv;
                float yb = accb[i][j][r] + db * xv;
                out[(size_t)row * 256 + h] = gelu_f(yf) + gelu_f(yb);
            }
        }
}

// ---------------- launcher ----------------
extern "C" void kernel_launch(void* const* d_in, const int* in_sizes, int n_in,
                              void* d_out, int out_size, void* d_ws, size_t ws_size,
                              hipStream_t stream) {
    const float* x   = (const float*)d_in[0];
    const float* fLr = (const float*)d_in[1];
    const float* fIm = (const float*)d_in[2];
    const float* fLd = (const float*)d_in[3];
    const float* fBr = (const float*)d_in[4];
    const float* fBi = (const float*)d_in[5];
    const float* fCr = (const float*)d_in[6];
    const float* fCi = (const float*)d_in[7];
    const float* fD  = (const float*)d_in[8];
    const float* bLr = (const float*)d_in[9];
    const float* bIm = (const float*)d_in[10];
    const float* bLd = (const float*)d_in[11];
    const float* bBr = (const float*)d_in[12];
    const float* bBi = (const float*)d_in[13];
    const float* bCr = (const float*)d_in[14];
    const float* bCi = (const float*)d_in[15];
    const float* bD  = (const float*)d_in[16];
    float* out = (float*)d_out;

    char* ws = (char*)d_ws;
    unsigned short* xbf  = (unsigned short*)(ws);                               // 16 MiB
    unsigned short* Bu   = (unsigned short*)(ws + 16777216);                    // 64 MiB (Bu, then xs in-place)
    unsigned short* Bmat = (unsigned short*)(ws + 16777216 + 67108864);         // 512 KiB
    unsigned short* B3   = (unsigned short*)(ws + 16777216 + 67108864 + 524288);// 512 KiB
    float2* LbarWS = (float2*)(ws + 16777216 + 67108864 + 1048576);             // 4 KiB
    float2* carry  = (float2*)(ws + 16777216 + 67108864 + 1048576 + 4096);      // 1 MiB

    prep_kernel<<<2050, 256, 0, stream>>>(fLr, fIm, fLd, fBr, fBi, fCr, fCi,
                                          bLr, bIm, bLd, bBr, bBi, bCr, bCi,
                                          Bmat, B3, LbarWS);
    xcast_kernel<<<8192, 256, 0, stream>>>((const float4*)x, (ushort4*)xbf);
    k1_gemm<<<dim3(256, 8), 256, 0, stream>>>(xbf, Bmat, Bu, LbarWS, carry);
    scan_fix_kernel<<<dim3(NC, 4), 512, 0, stream>>>((unsigned int*)Bu, LbarWS, carry);
    k3_gemm<<<dim3(256, 2), 256, 0, stream>>>(Bu, B3, xbf, fD, bD, out);
}

// Round 6
// 198.076 us; speedup vs baseline: 1.2975x; 1.0272x over previous
//
#include <hip/hip_runtime.h>
#include <math.h>

#define B_DIM 4
#define L_DIM 8192
#define H_DIM 256
#define P_DIM 256
#define M_DIM (B_DIM * L_DIM)   // 32768 rows (b,l) flattened
#define NC 64                   // scan chunks per chain (chunk = 128 rows = one k1 tile)
#define LC 128                  // chunk length

typedef __attribute__((ext_vector_type(8))) short bf16x8;
typedef __attribute__((ext_vector_type(4))) float f32x4;

static __device__ __forceinline__ float bf2f(unsigned int u) {
    union { unsigned int i; float f; } v; v.i = u << 16; return v.f;
}
static __device__ __forceinline__ unsigned short f2bf(float f) {
    union { float f; unsigned int i; } v; v.f = f;
    unsigned int r = v.i + 0x7FFFu + ((v.i >> 16) & 1u);
    return (unsigned short)(r >> 16);
}
// tanh-form GELU; |gelu_tanh - gelu_erf| <= ~0.003 absolute, far under threshold
static __device__ __forceinline__ float gelu_f(float x) {
    float z = 0.7978845608028654f * (x + 0.044715f * x * x * x);
    float e = __expf(2.0f * z);
    float t = 1.0f - 2.0f / (e + 1.0f);   // tanh(z)
    return 0.5f * x * (1.0f + t);
}
// async global->LDS DMA, 16B per lane; LDS dest = base + lane*16 (wave-uniform base)
static __device__ __forceinline__ void async_load16(const void* g, void* l) {
    __builtin_amdgcn_global_load_lds(
        (const __attribute__((address_space(1))) unsigned int*)g,
        (__attribute__((address_space(3))) unsigned int*)l, 16, 0, 0);
}

// ---------------- combined prep + xcast kernel ----------------
// gid < 2097152: xcast (float4 -> bf16x4).  Then Bmat / B3 / Lbar ranges.
// Layouts (INTERLEAVED complex): Bu col index k = d*512 + 2p + comp.
// Bmat[k][h] (1024x256 bf16); B3[d][h][k'] (2x256x512 bf16), k'=2p+comp;
// LbarWS[d*256+p] = (Lbar_r, Lbar_i) fp32.
__global__ void prep_kernel(const float* fLr, const float* fIm, const float* fLd,
                            const float* fBr, const float* fBi,
                            const float* fCr, const float* fCi,
                            const float* bLr, const float* bIm, const float* bLd,
                            const float* bBr, const float* bBi,
                            const float* bCr, const float* bCi,
                            const float4* __restrict__ x4, ushort4* __restrict__ xb,
                            unsigned short* Bmat, unsigned short* B3, float2* LbarWS) {
    int gid = blockIdx.x * 256 + threadIdx.x;
    if (gid < 2097152) {
        float4 v = x4[gid];
        ushort4 o;
        o.x = f2bf(v.x); o.y = f2bf(v.y); o.z = f2bf(v.z); o.w = f2bf(v.w);
        xb[gid] = o;
        return;
    }
    int g1 = gid - 2097152;
    if (g1 < 262144) {
        // Bmat
        int k = g1 >> 8, h = g1 & 255;
        int d = k >> 9, pc = k & 511, p = pc >> 1, comp = pc & 1;
        const float* LR = d ? bLr : fLr;
        const float* IM = d ? bIm : fIm;
        const float* LD = d ? bLd : fLd;
        const float* BR = d ? bBr : fBr;
        const float* BI = d ? bBi : fBi;
        float Lr = -expf(LR[p]);
        float Li = IM[p];
        float Delta = expf(LD[p]);
        float ea = expf(Lr * Delta);
        float bd = Li * Delta;
        float Lbr = ea * cosf(bd);
        float Lbi = ea * sinf(bd);
        float denom = fmaxf(Lr * Lr + Li * Li, 1e-12f);
        float ivr = Lr / denom, ivi = -Li / denom;
        float dr = Lbr - 1.0f, di = Lbi;
        float cr = ivr * dr - ivi * di;
        float ci = ivr * di + ivi * dr;
        float br = BR[p * 256 + h], bi = BI[p * 256 + h];
        float val = comp ? (cr * bi + ci * br) : (cr * br - ci * bi);
        Bmat[g1] = f2bf(val);
    } else if (g1 < 524288) {
        int g2 = g1 - 262144;
        int d = g2 >> 17;
        int rem = g2 & 131071;
        int h = rem >> 9;
        int kk = rem & 511;
        int p = kk >> 1, comp = kk & 1;
        const float* CR = d ? bCr : fCr;
        const float* CI = d ? bCi : fCi;
        float val = comp ? -CI[h * 256 + p] : CR[h * 256 + p];
        B3[g2] = f2bf(val);
    } else if (g1 < 524800) {
        int g2 = g1 - 524288;          // 0..511
        int d = g2 >> 8, p = g2 & 255;
        const float* LR = d ? bLr : fLr;
        const float* IM = d ? bIm : fIm;
        const float* LD = d ? bLd : fLd;
        float Lr = -expf(LR[p]); float Li = IM[p]; float Delta = expf(LD[p]);
        float ea = expf(Lr * Delta); float bd = Li * Delta;
        LbarWS[g2] = make_float2(ea * cosf(bd), ea * sinf(bd));
    }
}

// ---------------- K1: Bu = xbf(32768x256) @ Bmat(1024x256)^T -> Bu bf16 (32768x1024) ----------------
// m97 geometry: 256 threads / 4 waves, 128x128 tile, wave = 64x64 quadrant (4x4 f32x4 accs),
// BK=64, XOR-swizzled LDS chunks (16B chunk q of row r at q^(r&7); 0 conflicts verified).
// Epilogue: C tile -> LDS -> coalesced Bu store + fused per-chunk scan carries
// (full-chunk carry AND inner half-chunk partial, enabling 64-step scan_fix blocks).
__global__ __launch_bounds__(256, 2) void k1_gemm(const unsigned short* __restrict__ A,
                                                  const unsigned short* __restrict__ Bm,
                                                  unsigned short* __restrict__ Bu,
                                                  const float2* __restrict__ Lbar,
                                                  float2* __restrict__ carry,
                                                  float2* __restrict__ halfc) {
    __shared__ unsigned short SH[16384];   // 32 KB: As=SH[0:8192], Bs=SH[8192:16384]; Cs overlays all
    __shared__ float2 Sbuf[64];
    int tid = threadIdx.x;
    int lane = tid & 63, wv = tid >> 6;          // 4 waves
    int wm = (wv >> 1) * 64, wn = (wv & 1) * 64; // 64x64 quadrant
    int Mb = blockIdx.x * 128, Nb = blockIdx.y * 128;
    int lr = lane >> 3;                 // row within 8-row chunk group
    int swz = ((lane & 7) ^ lr) * 8;    // swizzled source chunk (in shorts)
    f32x4 acc[4][4];
#pragma unroll
    for (int i = 0; i < 4; i++)
#pragma unroll
        for (int j = 0; j < 4; j++) acc[i][j] = (f32x4){0.f, 0.f, 0.f, 0.f};
    int mrow = lane & 15, quad = lane >> 4;
    for (int kb = 0; kb < 256; kb += 64) {
#pragma unroll
        for (int ch = wv; ch < 16; ch += 4) {
            int r = ch * 8 + lr;
            async_load16(A  + (size_t)(Mb + r) * 256 + kb + swz, (char*)SH + ch * 1024);
            async_load16(Bm + (size_t)(Nb + r) * 256 + kb + swz, (char*)SH + 16384 + ch * 1024);
        }
        __syncthreads();
#pragma unroll
        for (int kk = 0; kk < 64; kk += 32) {
            bf16x8 af[4], bfr[4];
#pragma unroll
            for (int i = 0; i < 4; i++) {
                int rr = wm + 16 * i + mrow;
                af[i] = *(const bf16x8*)&SH[rr * 64 + ((((kk >> 3) + quad) ^ (rr & 7)) << 3)];
            }
#pragma unroll
            for (int j = 0; j < 4; j++) {
                int rr = wn + 16 * j + mrow;
                bfr[j] = *(const bf16x8*)&SH[8192 + rr * 64 + ((((kk >> 3) + quad) ^ (rr & 7)) << 3)];
            }
#pragma unroll
            for (int i = 0; i < 4; i++)
#pragma unroll
                for (int j = 0; j < 4; j++)
                    acc[i][j] = __builtin_amdgcn_mfma_f32_16x16x32_bf16(af[i], bfr[j], acc[i][j], 0, 0, 0);
        }
        __syncthreads();
    }
    // ---- epilogue: C tile (128x128 bf16) into LDS ----
    unsigned short* Cs = SH;
#pragma unroll
    for (int i = 0; i < 4; i++)
#pragma unroll
        for (int j = 0; j < 4; j++)
#pragma unroll
            for (int r = 0; r < 4; r++) {
                int row = wm + 16 * i + quad * 4 + r;
                int col = wn + 16 * j + mrow;
                Cs[row * 128 + col] = f2bf(acc[i][j][r]);
            }
    __syncthreads();
    // coalesced Cs -> Bu (uint4 per thread, 8 iters)
#pragma unroll
    for (int it = 0; it < 8; it++) {
        int o = tid * 16 + it * 4096;       // byte offset in Cs
        int row = o >> 8, colb = o & 255;
        uint4 v = *(const uint4*)((const char*)Cs + o);
        *(uint4*)((char*)Bu + (size_t)(Mb + row) * 2048 + (size_t)Nb * 2 + colb) = v;
    }
    // fused per-chunk scan carry: this block is chunk c of batch b, 64 complex chains.
    int d = Nb >> 9;
    int b = Mb >> 13;
    int c = (Mb >> 7) & 63;
    float sr = 0.f, si = 0.f;
    float2 A2 = make_float2(0.f, 0.f);
    int p = 0;
    if (tid < 128) {
        int j = tid & 63, half = tid >> 6;
        p = ((Nb & 511) >> 1) + j;
        A2 = Lbar[d * 256 + p];
        const unsigned int* C32 = (const unsigned int*)Cs;
        int r0 = half * 64;
        if (d == 0) {
            for (int t = 0; t < 64; t++) {
                unsigned int v = C32[(r0 + t) * 64 + j];
                float zr = bf2f(v & 0xffffu), zi = bf2f(v >> 16);
                float nr = A2.x * sr - A2.y * si + zr;
                float ni = A2.x * si + A2.y * sr + zi;
                sr = nr; si = ni;
            }
        } else {
            for (int t = 63; t >= 0; t--) {
                unsigned int v = C32[(r0 + t) * 64 + j];
                float zr = bf2f(v & 0xffffu), zi = bf2f(v >> 16);
                float nr = A2.x * sr - A2.y * si + zr;
                float ni = A2.x * si + A2.y * sr + zi;
                sr = nr; si = ni;
            }
        }
        if (half == 1) Sbuf[j] = make_float2(sr, si);
    }
    __syncthreads();
    if (tid < 64) {
        // here (sr,si) = half-0 partial: fwd S0 (rows 0..63), bwd S0' (rows 63..0)
        float2 S1 = Sbuf[tid];   // half-1 partial: fwd S1 (64..127), bwd S1' (127..64)
        float a64r = A2.x, a64i = A2.y;
#pragma unroll
        for (int k = 0; k < 6; k++) {  // A^(2^6) = A^64
            float nr = a64r * a64r - a64i * a64i;
            float ni = 2.f * a64r * a64i;
            a64r = nr; a64i = ni;
        }
        float cr, ci;
        float2 hv;
        if (d == 0) {   // full carry = A^64 * S0 + S1 ; inner partial = S0
            cr = a64r * sr - a64i * si + S1.x;
            ci = a64r * si + a64i * sr + S1.y;
            hv = make_float2(sr, si);
        } else {        // full carry = S0' + A^64 * S1' ; inner partial = S1'
            cr = sr + a64r * S1.x - a64i * S1.y;
            ci = si + a64r * S1.y + a64i * S1.x;
            hv = S1;
        }
        size_t cidx = ((size_t)(d * 4 + b) * NC + c) * 256 + p;
        carry[cidx] = make_float2(cr, ci);
        halfc[cidx] = hv;
    }
}

// ---------------- scan fix: half-chunk blocks (64 serial steps) ----------------
// grid (128 sub-chunks, 4 batches) x 512 thr: d = tid>>8 (wave-uniform), p = tid&255.
// sub-chunk m = 2c+h covers rows [c*128 + h*64, +64).
// fwd state entering: h=0 -> P(c) (combine carries j<c); h=1 -> A^64*P(c) + S0(c).
// bwd state entering: h=1 -> R(c) (combine carries j>c); h=0 -> A^64*R(c) + S1'(c).
__global__ __launch_bounds__(512) void scan_fix_kernel(unsigned int* __restrict__ XSu,
                                                       const float2* __restrict__ Lbar,
                                                       const float2* __restrict__ carry,
                                                       const float2* __restrict__ halfc) {
    int m = blockIdx.x, b = blockIdx.y;
    int c = m >> 1, h = m & 1;
    int d = threadIdx.x >> 8;
    int p = threadIdx.x & 255;
    float2 A = Lbar[d * 256 + p];
    float ar = A.x, ai = A.y;
    float a64r = ar, a64i = ai;
#pragma unroll
    for (int k = 0; k < 6; k++) {  // A^64
        float nr = a64r * a64r - a64i * a64i;
        float ni = 2.f * a64r * a64i;
        a64r = nr; a64i = ni;
    }
    float a128r = a64r * a64r - a64i * a64i;
    float a128i = 2.f * a64r * a64i;
    float sr = 0.f, si = 0.f;
    const float2* cb = carry + ((size_t)(d * 4 + b) * NC) * 256 + p;
    size_t hidx = ((size_t)(d * 4 + b) * NC + c) * 256 + p;
    if (d == 0) {
#pragma unroll 4
        for (int j = 0; j < c; j++) {
            float2 cj = cb[(size_t)j * 256];
            float nr = a128r * sr - a128i * si + cj.x;
            float ni = a128r * si + a128i * sr + cj.y;
            sr = nr; si = ni;
        }
        if (h) {
            float2 hc = halfc[hidx];
            float nr = a64r * sr - a64i * si + hc.x;
            float ni = a64r * si + a64i * sr + hc.y;
            sr = nr; si = ni;
        }
    } else {
#pragma unroll 4
        for (int j = NC - 1; j > c; j--) {
            float2 cj = cb[(size_t)j * 256];
            float nr = a128r * sr - a128i * si + cj.x;
            float ni = a128r * si + a128i * sr + cj.y;
            sr = nr; si = ni;
        }
        if (!h) {
            float2 hc = halfc[hidx];
            float nr = a64r * sr - a64i * si + hc.x;
            float ni = a64r * si + a64i * sr + hc.y;
            sr = nr; si = ni;
        }
    }
    size_t base = (size_t)b * L_DIM * 512 + d * 256 + p;
    int l0 = c * 128 + h * 64;
    if (d == 0) {
#pragma unroll 16
        for (int t = 0; t < 64; t++) {
            size_t idx = base + (size_t)(l0 + t) * 512;
            unsigned int v = XSu[idx];
            float zr = bf2f(v & 0xffffu), zi = bf2f(v >> 16);
            float nr = ar * sr - ai * si + zr;
            float ni = ar * si + ai * sr + zi;
            sr = nr; si = ni;
            XSu[idx] = (unsigned int)f2bf(sr) | ((unsigned int)f2bf(si) << 16);
        }
    } else {
#pragma unroll 16
        for (int t = 63; t >= 0; t--) {
            size_t idx = base + (size_t)(l0 + t) * 512;
            unsigned int v = XSu[idx];
            float zr = bf2f(v & 0xffffu), zi = bf2f(v >> 16);
            float nr = ar * sr - ai * si + zr;
            float ni = ar * si + ai * sr + zi;
            sr = nr; si = ni;
            XSu[idx] = (unsigned int)f2bf(sr) | ((unsigned int)f2bf(si) << 16);
        }
    }
}

// ---------------- K3 half: one K=512 GEMM with statically-bound accumulator ----------------
static __device__ __forceinline__ void k3_half(const unsigned short* __restrict__ XS,
                                               const unsigned short* __restrict__ B3h,
                                               unsigned short* As, unsigned short* Bs,
                                               int Mb, int Hb, int coff,
                                               int wm, int wn, int mrow, int quad,
                                               int lr, int swz, int wv,
                                               f32x4 (&acc)[4][4]) {
    for (int kb = 0; kb < 512; kb += 64) {
#pragma unroll
        for (int ch = wv; ch < 16; ch += 4) {
            int r = ch * 8 + lr;
            async_load16(XS + (size_t)(Mb + r) * 1024 + coff + kb + swz, (char*)As + ch * 1024);
            async_load16(B3h + (size_t)(Hb + r) * 512 + kb + swz, (char*)Bs + ch * 1024);
        }
        __syncthreads();
#pragma unroll
        for (int kk = 0; kk < 64; kk += 32) {
            bf16x8 af[4], bfr[4];
#pragma unroll
            for (int i = 0; i < 4; i++) {
                int rr = wm + 16 * i + mrow;
                af[i] = *(const bf16x8*)&As[rr * 64 + ((((kk >> 3) + quad) ^ (rr & 7)) << 3)];
            }
#pragma unroll
            for (int j = 0; j < 4; j++) {
                int rr = wn + 16 * j + mrow;
                bfr[j] = *(const bf16x8*)&Bs[rr * 64 + ((((kk >> 3) + quad) ^ (rr & 7)) << 3)];
            }
#pragma unroll
            for (int i = 0; i < 4; i++)
#pragma unroll
                for (int j = 0; j < 4; j++)
                    acc[i][j] = __builtin_amdgcn_mfma_f32_16x16x32_bf16(af[i], bfr[j], acc[i][j], 0, 0, 0);
        }
        __syncthreads();
    }
}

// ---------------- K3: out = gelu(xs_f·Cf + Df*x) + gelu(W·Cb + Db*x) ----------------
__global__ __launch_bounds__(256, 2) void k3_gemm(const unsigned short* __restrict__ XS,
                                                  const unsigned short* __restrict__ B3,
                                                  const unsigned short* __restrict__ xbf,
                                                  const float* __restrict__ Df,
                                                  const float* __restrict__ Db,
                                                  float* __restrict__ out) {
    __shared__ unsigned short As[128 * 64];
    __shared__ unsigned short Bs[128 * 64];
    int tid = threadIdx.x;
    int lane = tid & 63, wv = tid >> 6;          // 4 waves
    int wm = (wv >> 1) * 64, wn = (wv & 1) * 64; // 64x64 quadrant
    int Mb = blockIdx.x * 128, Hb = blockIdx.y * 128;
    int lr = lane >> 3;
    int swz = ((lane & 7) ^ lr) * 8;
    int mrow = lane & 15, quad = lane >> 4;
    f32x4 accf[4][4], accb[4][4];
#pragma unroll
    for (int i = 0; i < 4; i++)
#pragma unroll
        for (int j = 0; j < 4; j++) {
            accf[i][j] = (f32x4){0.f, 0.f, 0.f, 0.f};
            accb[i][j] = (f32x4){0.f, 0.f, 0.f, 0.f};
        }
    // forward half (k-cols 0..511), then backward half (512..1023) — statically bound accs
    k3_half(XS, B3,          As, Bs, Mb, Hb, 0,   wm, wn, mrow, quad, lr, swz, wv, accf);
    k3_half(XS, B3 + 131072, As, Bs, Mb, Hb, 512, wm, wn, mrow, quad, lr, swz, wv, accb);
#pragma unroll
    for (int i = 0; i < 4; i++)
#pragma unroll
        for (int j = 0; j < 4; j++) {
            int h = Hb + wn + 16 * j + mrow;
            float df = Df[h], db = Db[h];
#pragma unroll
            for (int r = 0; r < 4; r++) {
                int row = Mb + wm + 16 * i + quad * 4 + r;
                float xv = bf2f((unsigned int)xbf[(size_t)row * 256 + h]);
                float yf = accf[i][j][r] + df * xv;
                float yb = accb[i][j][r] + db * xv;
                out[(size_t)row * 256 + h] = gelu_f(yf) + gelu_f(yb);
            }
        }
}

// ---------------- launcher ----------------
extern "C" void kernel_launch(void* const* d_in, const int* in_sizes, int n_in,
                              void* d_out, int out_size, void* d_ws, size_t ws_size,
                              hipStream_t stream) {
    const float* x   = (const float*)d_in[0];
    const float* fLr = (const float*)d_in[1];
    const float* fIm = (const float*)d_in[2];
    const float* fLd = (const float*)d_in[3];
    const float* fBr = (const float*)d_in[4];
    const float* fBi = (const float*)d_in[5];
    const float* fCr = (const float*)d_in[6];
    const float* fCi = (const float*)d_in[7];
    const float* fD  = (const float*)d_in[8];
    const float* bLr = (const float*)d_in[9];
    const float* bIm = (const float*)d_in[10];
    const float* bLd = (const float*)d_in[11];
    const float* bBr = (const float*)d_in[12];
    const float* bBi = (const float*)d_in[13];
    const float* bCr = (const float*)d_in[14];
    const float* bCi = (const float*)d_in[15];
    const float* bD  = (const float*)d_in[16];
    float* out = (float*)d_out;

    char* ws = (char*)d_ws;
    unsigned short* xbf  = (unsigned short*)(ws);                               // 16 MiB
    unsigned short* Bu   = (unsigned short*)(ws + 16777216);                    // 64 MiB (Bu, then xs in-place)
    unsigned short* Bmat = (unsigned short*)(ws + 16777216 + 67108864);         // 512 KiB
    unsigned short* B3   = (unsigned short*)(ws + 16777216 + 67108864 + 524288);// 512 KiB
    float2* LbarWS = (float2*)(ws + 16777216 + 67108864 + 1048576);             // 4 KiB
    float2* carry  = (float2*)(ws + 16777216 + 67108864 + 1048576 + 4096);      // 1 MiB
    float2* halfc  = (float2*)(ws + 16777216 + 67108864 + 1048576 + 4096 + 1048576); // 1 MiB

    prep_kernel<<<10242, 256, 0, stream>>>(fLr, fIm, fLd, fBr, fBi, fCr, fCi,
                                           bLr, bIm, bLd, bBr, bBi, bCr, bCi,
                                           (const float4*)x, (ushort4*)xbf,
                                           Bmat, B3, LbarWS);
    k1_gemm<<<dim3(256, 8), 256, 0, stream>>>(xbf, Bmat, Bu, LbarWS, carry, halfc);
    scan_fix_kernel<<<dim3(128, 4), 512, 0, stream>>>((unsigned int*)Bu, LbarWS, carry, halfc);
    k3_gemm<<<dim3(256, 2), 256, 0, stream>>>(Bu, B3, xbf, fD, bD, out);
}